// Round 1
// baseline (1573.412 us; speedup 1.0000x reference)
//
#include <hip/hip_runtime.h>
#include <hip/hip_bf16.h>
#include <stdint.h>

#define BATCH  64
#define NFRAME 32
#define NBOX   36
#define REGION 1024
#define HIDDEN 1024
#define ATTSZ  1024
#define FEAT2  3072
#define M_S (BATCH * NFRAME * NBOX)   // 73728
#define M_T (BATCH * NFRAME)          // 2048

typedef __attribute__((ext_vector_type(8))) short bf16x8;
typedef __attribute__((ext_vector_type(4))) float f32x4;

__device__ __forceinline__ unsigned short f2bf(float f) {
  union { float f; uint32_t u; } v; v.f = f;
  return (unsigned short)((v.u + 0x7FFFu + ((v.u >> 16) & 1u)) >> 16);  // RNE
}

__device__ __forceinline__ float fast_tanh(float x) {
  float e = __expf(2.f * x);
  return 1.f - 2.f / (e + 1.f);
}

// ---------------------------------------------------------------------------
// Fused GEMM + tanh + row-score reduction.
//   C = A[M x K] @ W[1024 x K]^T   (bf16 MFMA, fp32 acc)
//   score[row] += sum_col tanh(C[row][col] + h[row/rows_per_b][col]) * wa[col]
// Tile 128x128, BK=64, 256 threads (4 waves in 2x2), LDS stride padded to 72.
// ---------------------------------------------------------------------------
#define BM 128
#define BN 128
#define BK 64
#define LDKP 72

__global__ __launch_bounds__(256) void fused_gemm_tanh_score(
    const float* __restrict__ A, const float* __restrict__ W,
    const float* __restrict__ hvec, const float* __restrict__ wa,
    float* __restrict__ score, int M, int K, int rows_per_b)
{
  __shared__ unsigned short ldsA[BM * LDKP];
  __shared__ unsigned short ldsW[BN * LDKP];
  const int tid  = threadIdx.x;
  const int lane = tid & 63;
  const int wid  = tid >> 6;
  const int wr   = (wid >> 1) * 64;   // wave row offset in tile
  const int wc   = (wid & 1) * 64;    // wave col offset in tile
  const int l15  = lane & 15;
  const int q    = lane >> 4;
  const long r0  = (long)blockIdx.y * BM;
  const int  c0  = blockIdx.x * BN;

  f32x4 acc[4][4] = {};

  for (int k0 = 0; k0 < K; k0 += BK) {
    __syncthreads();
    // Stage A tile: 128 rows x 64 k fp32 -> bf16 LDS (each thread 8 quads)
    #pragma unroll
    for (int it = 0; it < 8; ++it) {
      int c = tid + it * 256;
      int row = c >> 4;           // 16 quads per 64-wide row
      int qb  = c & 15;
      float4 s = *(const float4*)(A + (r0 + row) * (long)K + k0 + qb * 4);
      ushort4 d;
      d.x = f2bf(s.x); d.y = f2bf(s.y); d.z = f2bf(s.z); d.w = f2bf(s.w);
      *(ushort4*)(ldsA + row * LDKP + qb * 4) = d;
    }
    // Stage W tile (cols c0..c0+127 of W, i.e. rows of W since W is [1024][K])
    #pragma unroll
    for (int it = 0; it < 8; ++it) {
      int c = tid + it * 256;
      int row = c >> 4;
      int qb  = c & 15;
      float4 s = *(const float4*)(W + (c0 + row) * (long)K + k0 + qb * 4);
      ushort4 d;
      d.x = f2bf(s.x); d.y = f2bf(s.y); d.z = f2bf(s.z); d.w = f2bf(s.w);
      *(ushort4*)(ldsW + row * LDKP + qb * 4) = d;
    }
    __syncthreads();
    #pragma unroll
    for (int s = 0; s < 2; ++s) {   // two k-steps of 32
      bf16x8 af[4], bfr[4];
      #pragma unroll
      for (int i = 0; i < 4; ++i)
        af[i] = *(const bf16x8*)(ldsA + (wr + i * 16 + l15) * LDKP + s * 32 + q * 8);
      #pragma unroll
      for (int j = 0; j < 4; ++j)
        bfr[j] = *(const bf16x8*)(ldsW + (wc + j * 16 + l15) * LDKP + s * 32 + q * 8);
      #pragma unroll
      for (int i = 0; i < 4; ++i)
        #pragma unroll
        for (int j = 0; j < 4; ++j)
          acc[i][j] = __builtin_amdgcn_mfma_f32_16x16x32_bf16(af[i], bfr[j], acc[i][j], 0, 0, 0);
    }
  }

  // Epilogue: tanh(acc + h) * wa, reduce over cols -> atomicAdd per row.
  float wac[4];
  #pragma unroll
  for (int j = 0; j < 4; ++j) wac[j] = wa[c0 + wc + j * 16 + l15];

  #pragma unroll
  for (int i = 0; i < 4; ++i) {
    #pragma unroll
    for (int r = 0; r < 4; ++r) {
      int row = (int)r0 + wr + i * 16 + q * 4 + r;   // C/D: row = quad*4 + reg
      const float* hrow = hvec + (long)(row / rows_per_b) * ATTSZ;
      float part = 0.f;
      #pragma unroll
      for (int j = 0; j < 4; ++j) {
        int col = c0 + wc + j * 16 + l15;            // C/D: col = lane&15
        float x = acc[i][j][r] + hrow[col];
        part += fast_tanh(x) * wac[j];
      }
      part += __shfl_xor(part, 1);
      part += __shfl_xor(part, 2);
      part += __shfl_xor(part, 4);
      part += __shfl_xor(part, 8);
      if (l15 == 0) atomicAdd(score + row, part);
    }
  }
}

// ---------------------------------------------------------------------------
// h projections: h_s = hidden @ s_wh_w^T + s_wh_b + s_wv_b  (biases folded)
//                h_t = hidden @ t_wh_w^T + t_wh_b + t_wv_b
// One wave per output column a, all 64 batches accumulated in registers.
// ---------------------------------------------------------------------------
__global__ __launch_bounds__(256) void hidden_proj(
    const float* __restrict__ hidden,
    const float* __restrict__ s_wh_w, const float* __restrict__ s_wh_b,
    const float* __restrict__ s_wv_b,
    const float* __restrict__ t_wh_w, const float* __restrict__ t_wh_b,
    const float* __restrict__ t_wv_b,
    float* __restrict__ h_s, float* __restrict__ h_t)
{
  const float *W, *b1, *b2;
  float* out;
  if (blockIdx.y == 0) { W = s_wh_w; b1 = s_wh_b; b2 = s_wv_b; out = h_s; }
  else                 { W = t_wh_w; b1 = t_wh_b; b2 = t_wv_b; out = h_t; }
  const int lane = threadIdx.x & 63;
  const int wid  = threadIdx.x >> 6;
  const int a    = blockIdx.x * 4 + wid;
  __shared__ float hs[64 * 256];
  float acc[64];
  #pragma unroll
  for (int b = 0; b < 64; ++b) acc[b] = 0.f;

  for (int dc = 0; dc < 4; ++dc) {
    __syncthreads();
    for (int i = threadIdx.x; i < 4096; i += 256) {
      int b = i >> 6, d4 = i & 63;
      *(float4*)(hs + b * 256 + d4 * 4) =
          *(const float4*)(hidden + b * 1024 + dc * 256 + d4 * 4);
    }
    __syncthreads();
    float4 w4 = *(const float4*)(W + (long)a * 1024 + dc * 256 + lane * 4);
    #pragma unroll
    for (int b = 0; b < 64; ++b) {
      float4 h4 = *(const float4*)(hs + b * 256 + lane * 4);
      acc[b] += w4.x * h4.x + w4.y * h4.y + w4.z * h4.z + w4.w * h4.w;
    }
  }
  #pragma unroll
  for (int b = 0; b < 64; ++b) {
    #pragma unroll
    for (int off = 1; off < 64; off <<= 1)
      acc[b] += __shfl_xor(acc[b], off);
  }
  float res = 0.f;
  #pragma unroll
  for (int b = 0; b < 64; ++b)
    if (lane == b) res = acc[b];
  out[lane * 1024 + a] = res + b1[a] + b2[a];
}

// ---------------------------------------------------------------------------
// Spatial softmax over boxes + weighted sum -> feat[:, 0:1024] (fp32),
// plus copy of frame_feats -> feat[:, 1024:3072].
// ---------------------------------------------------------------------------
__global__ __launch_bounds__(256) void spatial_softmax_obj(
    const float* __restrict__ obj, const float* __restrict__ score,
    const float* __restrict__ frame, float* __restrict__ feat)
{
  const int bf = blockIdx.x;
  __shared__ float alpha[NBOX];
  if (threadIdx.x < 64) {
    int n = threadIdx.x;
    float v = (n < NBOX) ? score[bf * NBOX + n] : -1e30f;
    float m = v;
    #pragma unroll
    for (int off = 32; off; off >>= 1) m = fmaxf(m, __shfl_xor(m, off));
    float e = (n < NBOX) ? __expf(v - m) : 0.f;
    float ssum = e;
    #pragma unroll
    for (int off = 32; off; off >>= 1) ssum += __shfl_xor(ssum, off);
    if (n < NBOX) alpha[n] = e / ssum;
  }
  __syncthreads();
  const float* base = obj + (long)bf * NBOX * REGION;
  float4 av = {0.f, 0.f, 0.f, 0.f};
  for (int n = 0; n < NBOX; ++n) {
    float al = alpha[n];
    float4 o = *(const float4*)(base + n * REGION + threadIdx.x * 4);
    av.x += al * o.x; av.y += al * o.y; av.z += al * o.z; av.w += al * o.w;
  }
  float* frow = feat + (long)bf * FEAT2;
  *(float4*)(frow + threadIdx.x * 4) = av;
  const float4* fsrc = (const float4*)(frame + (long)bf * 2 * HIDDEN);
  float4* fdst = (float4*)(frow + REGION);
  fdst[threadIdx.x]       = fsrc[threadIdx.x];
  fdst[threadIdx.x + 256] = fsrc[threadIdx.x + 256];
}

// ---------------------------------------------------------------------------
// Temporal softmax over frames + weighted sum of feat -> out[B, 3072]
// ---------------------------------------------------------------------------
__global__ __launch_bounds__(256) void temporal_out(
    const float* __restrict__ score2, const float* __restrict__ feat,
    float* __restrict__ out)
{
  const int b = blockIdx.x;
  __shared__ float beta[NFRAME];
  if (threadIdx.x < 64) {
    int f = threadIdx.x;
    float v = (f < NFRAME) ? score2[b * NFRAME + f] : -1e30f;
    float m = v;
    #pragma unroll
    for (int off = 32; off; off >>= 1) m = fmaxf(m, __shfl_xor(m, off));
    float e = (f < NFRAME) ? __expf(v - m) : 0.f;
    float ssum = e;
    #pragma unroll
    for (int off = 32; off; off >>= 1) ssum += __shfl_xor(ssum, off);
    if (f < NFRAME) beta[f] = e / ssum;
  }
  __syncthreads();
  #pragma unroll
  for (int c = 0; c < 3; ++c) {
    int col = (threadIdx.x + c * 256) * 4;
    float4 av = {0.f, 0.f, 0.f, 0.f};
    for (int f = 0; f < NFRAME; ++f) {
      float bw = beta[f];
      float4 v = *(const float4*)(feat + (long)(b * NFRAME + f) * FEAT2 + col);
      av.x += bw * v.x; av.y += bw * v.y; av.z += bw * v.z; av.w += bw * v.w;
    }
    *(float4*)(out + (long)b * FEAT2 + col) = av;
  }
}

// ---------------------------------------------------------------------------
extern "C" void kernel_launch(void* const* d_in, const int* in_sizes, int n_in,
                              void* d_out, int out_size, void* d_ws, size_t ws_size,
                              hipStream_t stream) {
  const float* frame  = (const float*)d_in[0];
  const float* obj    = (const float*)d_in[1];
  const float* hidden = (const float*)d_in[2];
  const float* s_wh_w = (const float*)d_in[3];
  const float* s_wh_b = (const float*)d_in[4];
  const float* s_wv_w = (const float*)d_in[5];
  const float* s_wv_b = (const float*)d_in[6];
  const float* s_wa_w = (const float*)d_in[7];
  const float* t_wh_w = (const float*)d_in[8];
  const float* t_wh_b = (const float*)d_in[9];
  const float* t_wv_w = (const float*)d_in[10];
  const float* t_wv_b = (const float*)d_in[11];
  const float* t_wa_w = (const float*)d_in[12];
  float* out = (float*)d_out;

  float* ws      = (float*)d_ws;
  float* h_s     = ws;               // 64*1024
  float* h_t     = h_s + 65536;      // 64*1024
  float* score_s = h_t + 65536;      // 73728
  float* score2  = score_s + M_S;    // 2048
  float* feat    = score2 + M_T;     // 2048*3072 fp32

  hipMemsetAsync(score_s, 0, (M_S + M_T) * sizeof(float), stream);

  hidden_proj<<<dim3(256, 2), 256, 0, stream>>>(
      hidden, s_wh_w, s_wh_b, s_wv_b, t_wh_w, t_wh_b, t_wv_b, h_s, h_t);

  // Spatial: A = object_feats [73728 x 1024], W = s_wv_w [1024 x 1024]
  fused_gemm_tanh_score<<<dim3(8, M_S / 128), 256, 0, stream>>>(
      obj, s_wv_w, h_s, s_wa_w, score_s, M_S, REGION, NFRAME * NBOX);

  spatial_softmax_obj<<<M_T, 256, 0, stream>>>(obj, score_s, frame, feat);

  // Temporal: A = feat [2048 x 3072], W = t_wv_w [1024 x 3072]
  fused_gemm_tanh_score<<<dim3(8, M_T / 128), 256, 0, stream>>>(
      feat, t_wv_w, h_t, t_wa_w, score2, M_T, FEAT2, NFRAME);

  temporal_out<<<BATCH, 256, 0, stream>>>(score2, feat, out);
}

// Round 2
// 911.526 us; speedup vs baseline: 1.7261x; 1.7261x over previous
//
#include <hip/hip_runtime.h>
#include <hip/hip_bf16.h>
#include <stdint.h>

#define BATCH  64
#define NFRAME 32
#define NBOX   36
#define REGION 1024
#define HIDDEN 1024
#define ATTSZ  1024
#define FEAT2  3072
#define M_S (BATCH * NFRAME * NBOX)   // 73728
#define M_T (BATCH * NFRAME)          // 2048

typedef __attribute__((ext_vector_type(8))) short bf16x8;
typedef __attribute__((ext_vector_type(4))) float f32x4;

__device__ __forceinline__ unsigned short f2bf(float f) {
  union { float f; uint32_t u; } v; v.f = f;
  return (unsigned short)((v.u + 0x7FFFu + ((v.u >> 16) & 1u)) >> 16);  // RNE
}
__device__ __forceinline__ float bf2f(unsigned short u) {
  union { uint32_t u; float f; } v; v.u = (uint32_t)u << 16; return v.f;
}
__device__ __forceinline__ float fast_tanh(float x) {
  float e = __expf(2.f * x);
  return 1.f - 2.f / (e + 1.f);
}
__device__ __forceinline__ void gload_lds16(const unsigned short* g, unsigned short* l) {
  __builtin_amdgcn_global_load_lds(
      (const __attribute__((address_space(1))) unsigned int*)g,
      (__attribute__((address_space(3))) unsigned int*)l, 16, 0, 0);
}

// ---------------------------------------------------------------------------
// fp32 -> bf16 cast, 8 elems/thread, n % 8 == 0
// ---------------------------------------------------------------------------
__global__ __launch_bounds__(256) void cast_f32_bf16(
    const float* __restrict__ in, unsigned short* __restrict__ out, long n) {
  long i = ((long)blockIdx.x * 256 + threadIdx.x) * 8;
  if (i >= n) return;
  float4 a = *(const float4*)(in + i);
  float4 b = *(const float4*)(in + i + 4);
  ushort4 lo; lo.x = f2bf(a.x); lo.y = f2bf(a.y); lo.z = f2bf(a.z); lo.w = f2bf(a.w);
  ushort4 hi; hi.x = f2bf(b.x); hi.y = f2bf(b.y); hi.z = f2bf(b.z); hi.w = f2bf(b.w);
  *(ushort4*)(out + i) = lo;
  *(ushort4*)(out + i + 4) = hi;
}

// ---------------------------------------------------------------------------
// bf16 GEMM + tanh + row-score reduction (m97 structure).
//   score[row] += sum_col tanh( (A @ W^T)[row][col] + h[b(row)][col] ) * wa[col]
// A [M][K] bf16, W [1024][K] bf16. 128x128 tile, BK=64, global_load_lds
// staging (no VALU), n_col_tiles 128-col tiles looped inside the block.
// ---------------------------------------------------------------------------
#define BM 128
#define BN 128
#define BK 64

__global__ __launch_bounds__(256) void gemm_tanh_score_bf16(
    const unsigned short* __restrict__ A, const unsigned short* __restrict__ W,
    const float* __restrict__ hvec, const float* __restrict__ wa,
    float* __restrict__ score, int K, int rows_per_b, int n_col_tiles)
{
  __shared__ unsigned short ldsA[BM * BK];   // row-major, 64 bf16 per row
  __shared__ unsigned short ldsW[BN * BK];
  __shared__ float h_tile[4][BN];
  __shared__ float score_sh[2][BM];

  const int tid  = threadIdx.x;
  const int lane = tid & 63;
  const int wid  = tid >> 6;
  const int wr   = (wid >> 1) * 64;
  const int wc   = (wid & 1) * 64;
  const int l15  = lane & 15;
  const int q    = lane >> 4;
  const long r0  = (long)blockIdx.y * BM;
  const int srow = lane >> 3;     // row within an 8-row staging chunk
  const int sgr  = lane & 7;      // 16B granule within a 128B row segment

  const int b0 = (int)(r0 / rows_per_b);
  const int t1 = (b0 + 1) * rows_per_b - (int)r0;   // tile-local batch bounds
  const int t2 = t1 + rows_per_b;
  const int t3 = t2 + rows_per_b;

  float sreg[4][4] = {};   // per-(i,r) score partials, accumulated over col-tiles

  for (int t = 0; t < n_col_tiles; ++t) {
    const int c0 = (blockIdx.x * n_col_tiles + t) * BN;
    __syncthreads();   // prev col-tile's epilogue readers done before h_tile rewrite
    for (int idx = tid; idx < 4 * BN; idx += 256) {
      int bl = idx >> 7, c = idx & 127;
      int b = b0 + bl; if (b > BATCH - 1) b = BATCH - 1;
      h_tile[bl][c] = hvec[(long)b * ATTSZ + c0 + c];
    }
    float wac[4];
    #pragma unroll
    for (int j = 0; j < 4; ++j) wac[j] = wa[c0 + wc + j * 16 + l15];

    f32x4 acc[4][4] = {};
    for (int k0 = 0; k0 < K; k0 += BK) {
      __syncthreads();
      #pragma unroll
      for (int it = 0; it < 4; ++it) {
        int c = wid * 4 + it;            // chunk 0..15, 8 rows each
        int row = c * 8 + srow;
        gload_lds16(A + (r0 + row) * (long)K + k0 + sgr * 8, ldsA + c * 512);
        gload_lds16(W + (long)(c0 + row) * K + k0 + sgr * 8, ldsW + c * 512);
      }
      __syncthreads();
      #pragma unroll
      for (int s = 0; s < 2; ++s) {
        bf16x8 af[4], wf[4];
        #pragma unroll
        for (int i = 0; i < 4; ++i)
          af[i] = *(const bf16x8*)(ldsA + (wr + i * 16 + l15) * 64 + s * 32 + q * 8);
        #pragma unroll
        for (int j = 0; j < 4; ++j)
          wf[j] = *(const bf16x8*)(ldsW + (wc + j * 16 + l15) * 64 + s * 32 + q * 8);
        #pragma unroll
        for (int i = 0; i < 4; ++i)
          #pragma unroll
          for (int j = 0; j < 4; ++j)
            acc[i][j] = __builtin_amdgcn_mfma_f32_16x16x32_bf16(af[i], wf[j], acc[i][j], 0, 0, 0);
      }
    }
    // epilogue: tanh(acc + h) * wa, fold 4 cols per lane into sreg
    #pragma unroll
    for (int i = 0; i < 4; ++i) {
      #pragma unroll
      for (int r = 0; r < 4; ++r) {
        int lrow = wr + i * 16 + q * 4 + r;
        int bl = (lrow >= t1) + (lrow >= t2) + (lrow >= t3);
        float part = 0.f;
        #pragma unroll
        for (int j = 0; j < 4; ++j) {
          float x = acc[i][j][r] + h_tile[bl][wc + j * 16 + l15];
          part += fast_tanh(x) * wac[j];
        }
        sreg[i][r] += part;
      }
    }
  }
  // reduce over the 16 lanes of each quad (cols), then cross-wave via LDS
  #pragma unroll
  for (int i = 0; i < 4; ++i)
    #pragma unroll
    for (int r = 0; r < 4; ++r) {
      float v = sreg[i][r];
      v += __shfl_xor(v, 1); v += __shfl_xor(v, 2);
      v += __shfl_xor(v, 4); v += __shfl_xor(v, 8);
      sreg[i][r] = v;
    }
  if (l15 == 0) {
    #pragma unroll
    for (int i = 0; i < 4; ++i)
      #pragma unroll
      for (int r = 0; r < 4; ++r)
        score_sh[wid & 1][wr + i * 16 + q * 4 + r] = sreg[i][r];
  }
  __syncthreads();
  if (tid < BM)
    atomicAdd(score + r0 + tid, score_sh[0][tid] + score_sh[1][tid]);
}

// ---------------------------------------------------------------------------
// h projections (biases folded): h_s = hidden@s_wh_w^T + s_wh_b + s_wv_b, etc.
// ---------------------------------------------------------------------------
__global__ __launch_bounds__(256) void hidden_proj(
    const float* __restrict__ hidden,
    const float* __restrict__ s_wh_w, const float* __restrict__ s_wh_b,
    const float* __restrict__ s_wv_b,
    const float* __restrict__ t_wh_w, const float* __restrict__ t_wh_b,
    const float* __restrict__ t_wv_b,
    float* __restrict__ h_s, float* __restrict__ h_t)
{
  const float *W, *b1, *b2;
  float* out;
  if (blockIdx.y == 0) { W = s_wh_w; b1 = s_wh_b; b2 = s_wv_b; out = h_s; }
  else                 { W = t_wh_w; b1 = t_wh_b; b2 = t_wv_b; out = h_t; }
  const int lane = threadIdx.x & 63;
  const int wid  = threadIdx.x >> 6;
  const int a    = blockIdx.x * 4 + wid;
  __shared__ float hs[64 * 256];
  float acc[64];
  #pragma unroll
  for (int b = 0; b < 64; ++b) acc[b] = 0.f;

  for (int dc = 0; dc < 4; ++dc) {
    __syncthreads();
    for (int i = threadIdx.x; i < 4096; i += 256) {
      int b = i >> 6, d4 = i & 63;
      *(float4*)(hs + b * 256 + d4 * 4) =
          *(const float4*)(hidden + b * 1024 + dc * 256 + d4 * 4);
    }
    __syncthreads();
    float4 w4 = *(const float4*)(W + (long)a * 1024 + dc * 256 + lane * 4);
    #pragma unroll
    for (int b = 0; b < 64; ++b) {
      float4 h4 = *(const float4*)(hs + b * 256 + lane * 4);
      acc[b] += w4.x * h4.x + w4.y * h4.y + w4.z * h4.z + w4.w * h4.w;
    }
  }
  #pragma unroll
  for (int b = 0; b < 64; ++b) {
    #pragma unroll
    for (int off = 1; off < 64; off <<= 1)
      acc[b] += __shfl_xor(acc[b], off);
  }
  float res = 0.f;
  #pragma unroll
  for (int b = 0; b < 64; ++b)
    if (lane == b) res = acc[b];
  out[lane * 1024 + a] = res + b1[a] + b2[a];
}

// ---------------------------------------------------------------------------
// Spatial softmax + weighted sum (reads bf16 obj) -> feat fp32 + feat bf16
// ---------------------------------------------------------------------------
__global__ __launch_bounds__(256) void spatial_softmax_obj_bf16(
    const unsigned short* __restrict__ objb, const float* __restrict__ score,
    const float* __restrict__ frame, float* __restrict__ feat,
    unsigned short* __restrict__ featb)
{
  const int bf = blockIdx.x;
  __shared__ float alpha[NBOX];
  if (threadIdx.x < 64) {
    int n = threadIdx.x;
    float v = (n < NBOX) ? score[bf * NBOX + n] : -1e30f;
    float m = v;
    #pragma unroll
    for (int off = 32; off; off >>= 1) m = fmaxf(m, __shfl_xor(m, off));
    float e = (n < NBOX) ? __expf(v - m) : 0.f;
    float ssum = e;
    #pragma unroll
    for (int off = 32; off; off >>= 1) ssum += __shfl_xor(ssum, off);
    if (n < NBOX) alpha[n] = e / ssum;
  }
  __syncthreads();
  const unsigned short* base = objb + (long)bf * NBOX * REGION;
  float4 av = {0.f, 0.f, 0.f, 0.f};
  for (int n = 0; n < NBOX; ++n) {
    float al = alpha[n];
    ushort4 o = *(const ushort4*)(base + n * REGION + threadIdx.x * 4);
    av.x += al * bf2f(o.x); av.y += al * bf2f(o.y);
    av.z += al * bf2f(o.z); av.w += al * bf2f(o.w);
  }
  float* frow = feat + (long)bf * FEAT2;
  unsigned short* fbrow = featb + (long)bf * FEAT2;
  *(float4*)(frow + threadIdx.x * 4) = av;
  ushort4 avb; avb.x = f2bf(av.x); avb.y = f2bf(av.y); avb.z = f2bf(av.z); avb.w = f2bf(av.w);
  *(ushort4*)(fbrow + threadIdx.x * 4) = avb;
  const float* fsrc = frame + (long)bf * 2 * HIDDEN;
  #pragma unroll
  for (int c = 0; c < 2; ++c) {
    float4 v = *(const float4*)(fsrc + (threadIdx.x + c * 256) * 4);
    *(float4*)(frow + REGION + (threadIdx.x + c * 256) * 4) = v;
    ushort4 vb; vb.x = f2bf(v.x); vb.y = f2bf(v.y); vb.z = f2bf(v.z); vb.w = f2bf(v.w);
    *(ushort4*)(fbrow + REGION + (threadIdx.x + c * 256) * 4) = vb;
  }
}

// ---------------------------------------------------------------------------
// Temporal softmax + weighted sum of fp32 feat -> out[B, 3072]
// ---------------------------------------------------------------------------
__global__ __launch_bounds__(256) void temporal_out(
    const float* __restrict__ score2, const float* __restrict__ feat,
    float* __restrict__ out)
{
  const int b = blockIdx.x;
  __shared__ float beta[NFRAME];
  if (threadIdx.x < 64) {
    int f = threadIdx.x;
    float v = (f < NFRAME) ? score2[b * NFRAME + f] : -1e30f;
    float m = v;
    #pragma unroll
    for (int off = 32; off; off >>= 1) m = fmaxf(m, __shfl_xor(m, off));
    float e = (f < NFRAME) ? __expf(v - m) : 0.f;
    float ssum = e;
    #pragma unroll
    for (int off = 32; off; off >>= 1) ssum += __shfl_xor(ssum, off);
    if (f < NFRAME) beta[f] = e / ssum;
  }
  __syncthreads();
  #pragma unroll
  for (int c = 0; c < 3; ++c) {
    int col = (threadIdx.x + c * 256) * 4;
    float4 av = {0.f, 0.f, 0.f, 0.f};
    for (int f = 0; f < NFRAME; ++f) {
      float bw = beta[f];
      float4 v = *(const float4*)(feat + (long)(b * NFRAME + f) * FEAT2 + col);
      av.x += bw * v.x; av.y += bw * v.y; av.z += bw * v.z; av.w += bw * v.w;
    }
    *(float4*)(out + (long)b * FEAT2 + col) = av;
  }
}

// ===========================================================================
// Fallback path (round-1 kernels): fp32 inputs, inline bf16 conversion.
// Used only if ws_size can't hold the bf16 copies.
// ===========================================================================
#define LDKP 72
__global__ __launch_bounds__(256) void fused_gemm_tanh_score_f32(
    const float* __restrict__ A, const float* __restrict__ W,
    const float* __restrict__ hvec, const float* __restrict__ wa,
    float* __restrict__ score, int M, int K, int rows_per_b)
{
  __shared__ unsigned short ldsA[BM * LDKP];
  __shared__ unsigned short ldsW[BN * LDKP];
  const int tid  = threadIdx.x;
  const int lane = tid & 63;
  const int wid  = tid >> 6;
  const int wr   = (wid >> 1) * 64;
  const int wc   = (wid & 1) * 64;
  const int l15  = lane & 15;
  const int q    = lane >> 4;
  const long r0  = (long)blockIdx.y * BM;
  const int  c0  = blockIdx.x * BN;

  f32x4 acc[4][4] = {};
  for (int k0 = 0; k0 < K; k0 += BK) {
    __syncthreads();
    #pragma unroll
    for (int it = 0; it < 8; ++it) {
      int c = tid + it * 256;
      int row = c >> 4, qb = c & 15;
      float4 s = *(const float4*)(A + (r0 + row) * (long)K + k0 + qb * 4);
      ushort4 d; d.x = f2bf(s.x); d.y = f2bf(s.y); d.z = f2bf(s.z); d.w = f2bf(s.w);
      *(ushort4*)(ldsA + row * LDKP + qb * 4) = d;
    }
    #pragma unroll
    for (int it = 0; it < 8; ++it) {
      int c = tid + it * 256;
      int row = c >> 4, qb = c & 15;
      float4 s = *(const float4*)(W + (c0 + row) * (long)K + k0 + qb * 4);
      ushort4 d; d.x = f2bf(s.x); d.y = f2bf(s.y); d.z = f2bf(s.z); d.w = f2bf(s.w);
      *(ushort4*)(ldsW + row * LDKP + qb * 4) = d;
    }
    __syncthreads();
    #pragma unroll
    for (int s = 0; s < 2; ++s) {
      bf16x8 af[4], bfr[4];
      #pragma unroll
      for (int i = 0; i < 4; ++i)
        af[i] = *(const bf16x8*)(ldsA + (wr + i * 16 + l15) * LDKP + s * 32 + q * 8);
      #pragma unroll
      for (int j = 0; j < 4; ++j)
        bfr[j] = *(const bf16x8*)(ldsW + (wc + j * 16 + l15) * LDKP + s * 32 + q * 8);
      #pragma unroll
      for (int i = 0; i < 4; ++i)
        #pragma unroll
        for (int j = 0; j < 4; ++j)
          acc[i][j] = __builtin_amdgcn_mfma_f32_16x16x32_bf16(af[i], bfr[j], acc[i][j], 0, 0, 0);
    }
  }
  float wac[4];
  #pragma unroll
  for (int j = 0; j < 4; ++j) wac[j] = wa[c0 + wc + j * 16 + l15];
  #pragma unroll
  for (int i = 0; i < 4; ++i) {
    #pragma unroll
    for (int r = 0; r < 4; ++r) {
      int row = (int)r0 + wr + i * 16 + q * 4 + r;
      const float* hrow = hvec + (long)(row / rows_per_b) * ATTSZ;
      float part = 0.f;
      #pragma unroll
      for (int j = 0; j < 4; ++j) {
        float x = acc[i][j][r] + hrow[c0 + wc + j * 16 + l15];
        part += fast_tanh(x) * wac[j];
      }
      part += __shfl_xor(part, 1); part += __shfl_xor(part, 2);
      part += __shfl_xor(part, 4); part += __shfl_xor(part, 8);
      if (l15 == 0) atomicAdd(score + row, part);
    }
  }
}

__global__ __launch_bounds__(256) void spatial_softmax_obj_f32(
    const float* __restrict__ obj, const float* __restrict__ score,
    const float* __restrict__ frame, float* __restrict__ feat)
{
  const int bf = blockIdx.x;
  __shared__ float alpha[NBOX];
  if (threadIdx.x < 64) {
    int n = threadIdx.x;
    float v = (n < NBOX) ? score[bf * NBOX + n] : -1e30f;
    float m = v;
    #pragma unroll
    for (int off = 32; off; off >>= 1) m = fmaxf(m, __shfl_xor(m, off));
    float e = (n < NBOX) ? __expf(v - m) : 0.f;
    float ssum = e;
    #pragma unroll
    for (int off = 32; off; off >>= 1) ssum += __shfl_xor(ssum, off);
    if (n < NBOX) alpha[n] = e / ssum;
  }
  __syncthreads();
  const float* base = obj + (long)bf * NBOX * REGION;
  float4 av = {0.f, 0.f, 0.f, 0.f};
  for (int n = 0; n < NBOX; ++n) {
    float al = alpha[n];
    float4 o = *(const float4*)(base + n * REGION + threadIdx.x * 4);
    av.x += al * o.x; av.y += al * o.y; av.z += al * o.z; av.w += al * o.w;
  }
  float* frow = feat + (long)bf * FEAT2;
  *(float4*)(frow + threadIdx.x * 4) = av;
  const float4* fsrc = (const float4*)(frame + (long)bf * 2 * HIDDEN);
  float4* fdst = (float4*)(frow + REGION);
  fdst[threadIdx.x]       = fsrc[threadIdx.x];
  fdst[threadIdx.x + 256] = fsrc[threadIdx.x + 256];
}

// ---------------------------------------------------------------------------
extern "C" void kernel_launch(void* const* d_in, const int* in_sizes, int n_in,
                              void* d_out, int out_size, void* d_ws, size_t ws_size,
                              hipStream_t stream) {
  const float* frame  = (const float*)d_in[0];
  const float* obj    = (const float*)d_in[1];
  const float* hidden = (const float*)d_in[2];
  const float* s_wh_w = (const float*)d_in[3];
  const float* s_wh_b = (const float*)d_in[4];
  const float* s_wv_w = (const float*)d_in[5];
  const float* s_wv_b = (const float*)d_in[6];
  const float* s_wa_w = (const float*)d_in[7];
  const float* t_wh_w = (const float*)d_in[8];
  const float* t_wh_b = (const float*)d_in[9];
  const float* t_wv_w = (const float*)d_in[10];
  const float* t_wv_b = (const float*)d_in[11];
  const float* t_wa_w = (const float*)d_in[12];
  float* out = (float*)d_out;

  char* p = (char*)d_ws;
  auto alloc = [&](size_t bytes) { char* r = p; p += (bytes + 255) & ~255ull; return r; };
  float* h_s     = (float*)alloc(65536 * 4);
  float* h_t     = (float*)alloc(65536 * 4);
  float* score_s = (float*)alloc((size_t)M_S * 4);   // contiguous with score2
  float* score2  = (float*)alloc((size_t)M_T * 4);
  float* feat    = (float*)alloc((size_t)M_T * FEAT2 * 4);
  unsigned short* objb  = (unsigned short*)alloc((size_t)M_S * REGION * 2);
  unsigned short* featb = (unsigned short*)alloc((size_t)M_T * FEAT2 * 2);
  unsigned short* wvsb  = (unsigned short*)alloc((size_t)ATTSZ * REGION * 2);
  unsigned short* wvtb  = (unsigned short*)alloc((size_t)HIDDEN * FEAT2 * 2);
  size_t needed = (size_t)(p - (char*)d_ws);
  bool fast = needed <= ws_size;

  hipMemsetAsync(score_s, 0, (size_t)(M_S + M_T) * sizeof(float), stream);
  hidden_proj<<<dim3(256, 2), 256, 0, stream>>>(
      hidden, s_wh_w, s_wh_b, s_wv_b, t_wh_w, t_wh_b, t_wv_b, h_s, h_t);

  if (fast) {
    cast_f32_bf16<<<(M_S * (long)REGION) / 2048, 256, 0, stream>>>(obj, objb, (long)M_S * REGION);
    cast_f32_bf16<<<(ATTSZ * (long)REGION) / 2048, 256, 0, stream>>>(s_wv_w, wvsb, (long)ATTSZ * REGION);
    cast_f32_bf16<<<(HIDDEN * (long)FEAT2) / 2048, 256, 0, stream>>>(t_wv_w, wvtb, (long)HIDDEN * FEAT2);

    // Spatial: A = objb [73728 x 1024], 2 col-split blocks x 4 col-tiles each
    gemm_tanh_score_bf16<<<dim3(2, M_S / BM), 256, 0, stream>>>(
        objb, wvsb, h_s, s_wa_w, score_s, REGION, NFRAME * NBOX, 4);

    spatial_softmax_obj_bf16<<<M_T, 256, 0, stream>>>(objb, score_s, frame, feat, featb);

    // Temporal: A = featb [2048 x 3072], 8 col blocks x 1 tile
    gemm_tanh_score_bf16<<<dim3(8, M_T / BM), 256, 0, stream>>>(
        featb, wvtb, h_t, t_wa_w, score2, FEAT2, NFRAME, 1);
  } else {
    fused_gemm_tanh_score_f32<<<dim3(8, M_S / BM), 256, 0, stream>>>(
        obj, s_wv_w, h_s, s_wa_w, score_s, M_S, REGION, NFRAME * NBOX);
    spatial_softmax_obj_f32<<<M_T, 256, 0, stream>>>(obj, score_s, frame, feat);
    fused_gemm_tanh_score_f32<<<dim3(8, M_T / BM), 256, 0, stream>>>(
        feat, t_wv_w, h_t, t_wa_w, score2, M_T, FEAT2, NFRAME);
  }

  temporal_out<<<BATCH, 256, 0, stream>>>(score2, feat, out);
}

// Round 3
// 789.516 us; speedup vs baseline: 1.9929x; 1.1545x over previous
//
#include <hip/hip_runtime.h>
#include <hip/hip_bf16.h>
#include <stdint.h>

#define BATCH  64
#define NFRAME 32
#define NBOX   36
#define REGION 1024
#define HIDDEN 1024
#define ATTSZ  1024
#define FEAT2  3072
#define M_S (BATCH * NFRAME * NBOX)   // 73728
#define M_T (BATCH * NFRAME)          // 2048

typedef __attribute__((ext_vector_type(8))) short bf16x8;
typedef __attribute__((ext_vector_type(4))) float f32x4;

__device__ __forceinline__ unsigned short f2bf(float f) {
  union { float f; uint32_t u; } v; v.f = f;
  return (unsigned short)((v.u + 0x7FFFu + ((v.u >> 16) & 1u)) >> 16);  // RNE
}
__device__ __forceinline__ float bf2f(unsigned short u) {
  union { uint32_t u; float f; } v; v.u = (uint32_t)u << 16; return v.f;
}
__device__ __forceinline__ float fast_tanh(float x) {
  float e = __expf(2.f * x);
  return 1.f - 2.f / (e + 1.f);
}
__device__ __forceinline__ void gload_lds16(const unsigned short* g, unsigned short* l) {
  __builtin_amdgcn_global_load_lds(
      (const __attribute__((address_space(1))) unsigned int*)g,
      (__attribute__((address_space(3))) unsigned int*)l, 16, 0, 0);
}

// ---------------------------------------------------------------------------
// fp32 -> bf16 cast, 8 elems/thread
// ---------------------------------------------------------------------------
__global__ __launch_bounds__(256) void cast_f32_bf16(
    const float* __restrict__ in, unsigned short* __restrict__ out, long n) {
  long i = ((long)blockIdx.x * 256 + threadIdx.x) * 8;
  if (i >= n) return;
  float4 a = *(const float4*)(in + i);
  float4 b = *(const float4*)(in + i + 4);
  ushort4 lo; lo.x = f2bf(a.x); lo.y = f2bf(a.y); lo.z = f2bf(a.z); lo.w = f2bf(a.w);
  ushort4 hi; hi.x = f2bf(b.x); hi.y = f2bf(b.y); hi.z = f2bf(b.z); hi.w = f2bf(b.w);
  *(ushort4*)(out + i) = lo;
  *(ushort4*)(out + i + 4) = hi;
}

// ---------------------------------------------------------------------------
// Templated bf16 GEMM + tanh + row-score reduction.
//   score[row] += sum_col tanh( (A @ W^T)[row][col] + h[b(row)][col] ) * wa[col]
// Block = 256 threads = 4 waves in 2x2; wave tile (TM*16) x (TN*16);
// block tile BM=2*TM*16 rows x BN=2*TN*16 cols. BK=64, global_load_lds.
// REQUIRES: row tiles batch-aligned (BM divides rows_per_b or equals it).
// ---------------------------------------------------------------------------
template<int TM, int TN>
__global__ __launch_bounds__(256, 2) void gemm_tanh_score(
    const unsigned short* __restrict__ A, const unsigned short* __restrict__ W,
    const float* __restrict__ hvec, const float* __restrict__ wa,
    float* __restrict__ score, int K, int rows_per_b)
{
  constexpr int BM = 2 * TM * 16;
  constexpr int BN = 2 * TN * 16;
  __shared__ __align__(16) unsigned short ldsA[BM * 64];
  __shared__ __align__(16) unsigned short ldsW[BN * 64];
  __shared__ float h_tile[BN];
  __shared__ float score_sh[2][BM];

  const int tid  = threadIdx.x;
  const int lane = tid & 63;
  const int wid  = tid >> 6;
  const int wr   = (wid >> 1) * (TM * 16);
  const int wc   = (wid & 1) * (TN * 16);
  const int l15  = lane & 15;
  const int q    = lane >> 4;
  const long r0  = (long)blockIdx.y * BM;
  const int  c0  = blockIdx.x * BN;
  const int srow = lane >> 3;
  const int sgr  = lane & 7;
  const int b0   = (int)(r0 / rows_per_b);   // tile lies in one batch

  for (int i = tid; i < BN; i += 256)
    h_tile[i] = hvec[(long)b0 * ATTSZ + c0 + i];
  float wac[TN];
  #pragma unroll
  for (int j = 0; j < TN; ++j) wac[j] = wa[c0 + wc + j * 16 + l15];

  f32x4 acc[TM][TN] = {};

  for (int k0 = 0; k0 < K; k0 += 64) {
    __syncthreads();
    #pragma unroll
    for (int it = 0; it < BM / 32; ++it) {
      int c = wid * (BM / 32) + it;          // 8-row chunk
      gload_lds16(A + (r0 + c * 8 + srow) * (long)K + k0 + sgr * 8, ldsA + c * 512);
    }
    #pragma unroll
    for (int it = 0; it < BN / 32; ++it) {
      int c = wid * (BN / 32) + it;
      gload_lds16(W + ((long)(c0 + c * 8 + srow)) * K + k0 + sgr * 8, ldsW + c * 512);
    }
    __syncthreads();
    #pragma unroll
    for (int s = 0; s < 2; ++s) {
      bf16x8 af[TM], wf[TN];
      #pragma unroll
      for (int i = 0; i < TM; ++i)
        af[i] = *(const bf16x8*)(ldsA + (wr + i * 16 + l15) * 64 + s * 32 + q * 8);
      #pragma unroll
      for (int j = 0; j < TN; ++j)
        wf[j] = *(const bf16x8*)(ldsW + (wc + j * 16 + l15) * 64 + s * 32 + q * 8);
      #pragma unroll
      for (int i = 0; i < TM; ++i)
        #pragma unroll
        for (int j = 0; j < TN; ++j)
          acc[i][j] = __builtin_amdgcn_mfma_f32_16x16x32_bf16(af[i], wf[j], acc[i][j], 0, 0, 0);
    }
  }

  // Epilogue: tanh(acc + h) * wa, quad-reduce over the 16 col-lanes.
  #pragma unroll
  for (int i = 0; i < TM; ++i) {
    #pragma unroll
    for (int r = 0; r < 4; ++r) {
      float part = 0.f;
      #pragma unroll
      for (int j = 0; j < TN; ++j) {
        float x = acc[i][j][r] + h_tile[wc + j * 16 + l15];
        part += fast_tanh(x) * wac[j];
      }
      part += __shfl_xor(part, 1); part += __shfl_xor(part, 2);
      part += __shfl_xor(part, 4); part += __shfl_xor(part, 8);
      if (l15 == 0) score_sh[wid & 1][wr + i * 16 + q * 4 + r] = part;
    }
  }
  __syncthreads();
  if (tid < BM)
    atomicAdd(score + r0 + tid, score_sh[0][tid] + score_sh[1][tid]);
}

// ---------------------------------------------------------------------------
// h projections (biases folded)
// ---------------------------------------------------------------------------
__global__ __launch_bounds__(256) void hidden_proj(
    const float* __restrict__ hidden,
    const float* __restrict__ s_wh_w, const float* __restrict__ s_wh_b,
    const float* __restrict__ s_wv_b,
    const float* __restrict__ t_wh_w, const float* __restrict__ t_wh_b,
    const float* __restrict__ t_wv_b,
    float* __restrict__ h_s, float* __restrict__ h_t)
{
  const float *W, *b1, *b2;
  float* out;
  if (blockIdx.y == 0) { W = s_wh_w; b1 = s_wh_b; b2 = s_wv_b; out = h_s; }
  else                 { W = t_wh_w; b1 = t_wh_b; b2 = t_wv_b; out = h_t; }
  const int lane = threadIdx.x & 63;
  const int wid  = threadIdx.x >> 6;
  const int a    = blockIdx.x * 4 + wid;
  __shared__ float hs[64 * 256];
  float acc[64];
  #pragma unroll
  for (int b = 0; b < 64; ++b) acc[b] = 0.f;

  for (int dc = 0; dc < 4; ++dc) {
    __syncthreads();
    for (int i = threadIdx.x; i < 4096; i += 256) {
      int b = i >> 6, d4 = i & 63;
      *(float4*)(hs + b * 256 + d4 * 4) =
          *(const float4*)(hidden + b * 1024 + dc * 256 + d4 * 4);
    }
    __syncthreads();
    float4 w4 = *(const float4*)(W + (long)a * 1024 + dc * 256 + lane * 4);
    #pragma unroll
    for (int b = 0; b < 64; ++b) {
      float4 h4 = *(const float4*)(hs + b * 256 + lane * 4);
      acc[b] += w4.x * h4.x + w4.y * h4.y + w4.z * h4.z + w4.w * h4.w;
    }
  }
  #pragma unroll
  for (int b = 0; b < 64; ++b) {
    #pragma unroll
    for (int off = 1; off < 64; off <<= 1)
      acc[b] += __shfl_xor(acc[b], off);
  }
  float res = 0.f;
  #pragma unroll
  for (int b = 0; b < 64; ++b)
    if (lane == b) res = acc[b];
  out[lane * 1024 + a] = res + b1[a] + b2[a];
}

// ---------------------------------------------------------------------------
// Spatial softmax + weighted sum (bf16 obj) -> feat fp32 + feat bf16
// ---------------------------------------------------------------------------
__global__ __launch_bounds__(256) void spatial_softmax_obj_bf16(
    const unsigned short* __restrict__ objb, const float* __restrict__ score,
    const float* __restrict__ frame, float* __restrict__ feat,
    unsigned short* __restrict__ featb)
{
  const int bf = blockIdx.x;
  __shared__ float alpha[NBOX];
  if (threadIdx.x < 64) {
    int n = threadIdx.x;
    float v = (n < NBOX) ? score[bf * NBOX + n] : -1e30f;
    float m = v;
    #pragma unroll
    for (int off = 32; off; off >>= 1) m = fmaxf(m, __shfl_xor(m, off));
    float e = (n < NBOX) ? __expf(v - m) : 0.f;
    float ssum = e;
    #pragma unroll
    for (int off = 32; off; off >>= 1) ssum += __shfl_xor(ssum, off);
    if (n < NBOX) alpha[n] = e / ssum;
  }
  __syncthreads();
  const unsigned short* base = objb + (long)bf * NBOX * REGION;
  float4 av = {0.f, 0.f, 0.f, 0.f};
  for (int n = 0; n < NBOX; ++n) {
    float al = alpha[n];
    ushort4 o = *(const ushort4*)(base + n * REGION + threadIdx.x * 4);
    av.x += al * bf2f(o.x); av.y += al * bf2f(o.y);
    av.z += al * bf2f(o.z); av.w += al * bf2f(o.w);
  }
  float* frow = feat + (long)bf * FEAT2;
  unsigned short* fbrow = featb + (long)bf * FEAT2;
  *(float4*)(frow + threadIdx.x * 4) = av;
  ushort4 avb; avb.x = f2bf(av.x); avb.y = f2bf(av.y); avb.z = f2bf(av.z); avb.w = f2bf(av.w);
  *(ushort4*)(fbrow + threadIdx.x * 4) = avb;
  const float* fsrc = frame + (long)bf * 2 * HIDDEN;
  #pragma unroll
  for (int c = 0; c < 2; ++c) {
    float4 v = *(const float4*)(fsrc + (threadIdx.x + c * 256) * 4);
    *(float4*)(frow + REGION + (threadIdx.x + c * 256) * 4) = v;
    ushort4 vb; vb.x = f2bf(v.x); vb.y = f2bf(v.y); vb.z = f2bf(v.z); vb.w = f2bf(v.w);
    *(ushort4*)(fbrow + REGION + (threadIdx.x + c * 256) * 4) = vb;
  }
}

// ---------------------------------------------------------------------------
// Temporal softmax + weighted sum of fp32 feat -> out[B, 3072]
// ---------------------------------------------------------------------------
__global__ __launch_bounds__(256) void temporal_out(
    const float* __restrict__ score2, const float* __restrict__ feat,
    float* __restrict__ out)
{
  const int b = blockIdx.x;
  __shared__ float beta[NFRAME];
  if (threadIdx.x < 64) {
    int f = threadIdx.x;
    float v = (f < NFRAME) ? score2[b * NFRAME + f] : -1e30f;
    float m = v;
    #pragma unroll
    for (int off = 32; off; off >>= 1) m = fmaxf(m, __shfl_xor(m, off));
    float e = (f < NFRAME) ? __expf(v - m) : 0.f;
    float ssum = e;
    #pragma unroll
    for (int off = 32; off; off >>= 1) ssum += __shfl_xor(ssum, off);
    if (f < NFRAME) beta[f] = e / ssum;
  }
  __syncthreads();
  #pragma unroll
  for (int c = 0; c < 3; ++c) {
    int col = (threadIdx.x + c * 256) * 4;
    float4 av = {0.f, 0.f, 0.f, 0.f};
    for (int f = 0; f < NFRAME; ++f) {
      float bw = beta[f];
      float4 v = *(const float4*)(feat + (long)(b * NFRAME + f) * FEAT2 + col);
      av.x += bw * v.x; av.y += bw * v.y; av.z += bw * v.z; av.w += bw * v.w;
    }
    *(float4*)(out + (long)b * FEAT2 + col) = av;
  }
}

// ===========================================================================
// Fallback path (fp32 inputs, inline conversion) — only if ws too small.
// ===========================================================================
#define FBM 128
#define FBN 128
#define FBK 64
#define LDKP 72
__global__ __launch_bounds__(256) void fused_gemm_tanh_score_f32(
    const float* __restrict__ A, const float* __restrict__ W,
    const float* __restrict__ hvec, const float* __restrict__ wa,
    float* __restrict__ score, int M, int K, int rows_per_b)
{
  __shared__ unsigned short ldsA[FBM * LDKP];
  __shared__ unsigned short ldsW[FBN * LDKP];
  const int tid  = threadIdx.x;
  const int lane = tid & 63;
  const int wid  = tid >> 6;
  const int wr   = (wid >> 1) * 64;
  const int wc   = (wid & 1) * 64;
  const int l15  = lane & 15;
  const int q    = lane >> 4;
  const long r0  = (long)blockIdx.y * FBM;
  const int  c0  = blockIdx.x * FBN;

  f32x4 acc[4][4] = {};
  for (int k0 = 0; k0 < K; k0 += FBK) {
    __syncthreads();
    #pragma unroll
    for (int it = 0; it < 8; ++it) {
      int c = tid + it * 256;
      int row = c >> 4, qb = c & 15;
      float4 s = *(const float4*)(A + (r0 + row) * (long)K + k0 + qb * 4);
      ushort4 d; d.x = f2bf(s.x); d.y = f2bf(s.y); d.z = f2bf(s.z); d.w = f2bf(s.w);
      *(ushort4*)(ldsA + row * LDKP + qb * 4) = d;
    }
    #pragma unroll
    for (int it = 0; it < 8; ++it) {
      int c = tid + it * 256;
      int row = c >> 4, qb = c & 15;
      float4 s = *(const float4*)(W + (c0 + row) * (long)K + k0 + qb * 4);
      ushort4 d; d.x = f2bf(s.x); d.y = f2bf(s.y); d.z = f2bf(s.z); d.w = f2bf(s.w);
      *(ushort4*)(ldsW + row * LDKP + qb * 4) = d;
    }
    __syncthreads();
    #pragma unroll
    for (int s = 0; s < 2; ++s) {
      bf16x8 af[4], bfr[4];
      #pragma unroll
      for (int i = 0; i < 4; ++i)
        af[i] = *(const bf16x8*)(ldsA + (wr + i * 16 + l15) * LDKP + s * 32 + q * 8);
      #pragma unroll
      for (int j = 0; j < 4; ++j)
        bfr[j] = *(const bf16x8*)(ldsW + (wc + j * 16 + l15) * LDKP + s * 32 + q * 8);
      #pragma unroll
      for (int i = 0; i < 4; ++i)
        #pragma unroll
        for (int j = 0; j < 4; ++j)
          acc[i][j] = __builtin_amdgcn_mfma_f32_16x16x32_bf16(af[i], bfr[j], acc[i][j], 0, 0, 0);
    }
  }
  float wac[4];
  #pragma unroll
  for (int j = 0; j < 4; ++j) wac[j] = wa[c0 + wc + j * 16 + l15];
  #pragma unroll
  for (int i = 0; i < 4; ++i) {
    #pragma unroll
    for (int r = 0; r < 4; ++r) {
      int row = (int)r0 + wr + i * 16 + q * 4 + r;
      const float* hrow = hvec + (long)(row / rows_per_b) * ATTSZ;
      float part = 0.f;
      #pragma unroll
      for (int j = 0; j < 4; ++j) {
        float x = acc[i][j][r] + hrow[c0 + wc + j * 16 + l15];
        part += fast_tanh(x) * wac[j];
      }
      part += __shfl_xor(part, 1); part += __shfl_xor(part, 2);
      part += __shfl_xor(part, 4); part += __shfl_xor(part, 8);
      if (l15 == 0) atomicAdd(score + row, part);
    }
  }
}

__global__ __launch_bounds__(256) void spatial_softmax_obj_f32(
    const float* __restrict__ obj, const float* __restrict__ score,
    const float* __restrict__ frame, float* __restrict__ feat)
{
  const int bf = blockIdx.x;
  __shared__ float alpha[NBOX];
  if (threadIdx.x < 64) {
    int n = threadIdx.x;
    float v = (n < NBOX) ? score[bf * NBOX + n] : -1e30f;
    float m = v;
    #pragma unroll
    for (int off = 32; off; off >>= 1) m = fmaxf(m, __shfl_xor(m, off));
    float e = (n < NBOX) ? __expf(v - m) : 0.f;
    float ssum = e;
    #pragma unroll
    for (int off = 32; off; off >>= 1) ssum += __shfl_xor(ssum, off);
    if (n < NBOX) alpha[n] = e / ssum;
  }
  __syncthreads();
  const float* base = obj + (long)bf * NBOX * REGION;
  float4 av = {0.f, 0.f, 0.f, 0.f};
  for (int n = 0; n < NBOX; ++n) {
    float al = alpha[n];
    float4 o = *(const float4*)(base + n * REGION + threadIdx.x * 4);
    av.x += al * o.x; av.y += al * o.y; av.z += al * o.z; av.w += al * o.w;
  }
  float* frow = feat + (long)bf * FEAT2;
  *(float4*)(frow + threadIdx.x * 4) = av;
  const float4* fsrc = (const float4*)(frame + (long)bf * 2 * HIDDEN);
  float4* fdst = (float4*)(frow + REGION);
  fdst[threadIdx.x]       = fsrc[threadIdx.x];
  fdst[threadIdx.x + 256] = fsrc[threadIdx.x + 256];
}

// ---------------------------------------------------------------------------
extern "C" void kernel_launch(void* const* d_in, const int* in_sizes, int n_in,
                              void* d_out, int out_size, void* d_ws, size_t ws_size,
                              hipStream_t stream) {
  const float* frame  = (const float*)d_in[0];
  const float* obj    = (const float*)d_in[1];
  const float* hidden = (const float*)d_in[2];
  const float* s_wh_w = (const float*)d_in[3];
  const float* s_wh_b = (const float*)d_in[4];
  const float* s_wv_w = (const float*)d_in[5];
  const float* s_wv_b = (const float*)d_in[6];
  const float* s_wa_w = (const float*)d_in[7];
  const float* t_wh_w = (const float*)d_in[8];
  const float* t_wh_b = (const float*)d_in[9];
  const float* t_wv_w = (const float*)d_in[10];
  const float* t_wv_b = (const float*)d_in[11];
  const float* t_wa_w = (const float*)d_in[12];
  float* out = (float*)d_out;

  char* p = (char*)d_ws;
  auto alloc = [&](size_t bytes) { char* r = p; p += (bytes + 255) & ~255ull; return r; };
  float* h_s     = (float*)alloc(65536 * 4);
  float* h_t     = (float*)alloc(65536 * 4);
  float* score_s = (float*)alloc((size_t)M_S * 4);   // contiguous with score2
  float* score2  = (float*)alloc((size_t)M_T * 4);
  float* feat    = (float*)alloc((size_t)M_T * FEAT2 * 4);
  unsigned short* objb  = (unsigned short*)alloc((size_t)M_S * REGION * 2);
  unsigned short* featb = (unsigned short*)alloc((size_t)M_T * FEAT2 * 2);
  unsigned short* wvsb  = (unsigned short*)alloc((size_t)ATTSZ * REGION * 2);
  unsigned short* wvtb  = (unsigned short*)alloc((size_t)HIDDEN * FEAT2 * 2);
  size_t needed = (size_t)(p - (char*)d_ws);
  bool fast = needed <= ws_size;

  hipMemsetAsync(score_s, 0, (size_t)(M_S + M_T) * sizeof(float), stream);
  hidden_proj<<<dim3(256, 2), 256, 0, stream>>>(
      hidden, s_wh_w, s_wh_b, s_wv_b, t_wh_w, t_wh_b, t_wv_b, h_s, h_t);

  if (fast) {
    cast_f32_bf16<<<(M_S * (long)REGION) / 2048, 256, 0, stream>>>(obj, objb, (long)M_S * REGION);
    cast_f32_bf16<<<(ATTSZ * (long)REGION) / 2048, 256, 0, stream>>>(s_wv_w, wvsb, (long)ATTSZ * REGION);
    cast_f32_bf16<<<(HIDDEN * (long)FEAT2) / 2048, 256, 0, stream>>>(t_wv_w, wvtb, (long)HIDDEN * FEAT2);

    // Spatial: 128x256 tiles, grid (4, 576); col-siblings adjacent -> L3 shares A.
    gemm_tanh_score<4, 8><<<dim3(4, M_S / 128), 256, 0, stream>>>(
        objb, wvsb, h_s, s_wa_w, score_s, REGION, NFRAME * NBOX);

    spatial_softmax_obj_bf16<<<M_T, 256, 0, stream>>>(objb, score_s, frame, feat, featb);

    // Temporal: 32x128 tiles, grid (8, 64) = 512 blocks (2/CU).
    gemm_tanh_score<1, 4><<<dim3(8, M_T / 32), 256, 0, stream>>>(
        featb, wvtb, h_t, t_wa_w, score2, FEAT2, NFRAME);
  } else {
    fused_gemm_tanh_score_f32<<<dim3(8, M_S / FBM), 256, 0, stream>>>(
        obj, s_wv_w, h_s, s_wa_w, score_s, M_S, REGION, NFRAME * NBOX);
    spatial_softmax_obj_f32<<<M_T, 256, 0, stream>>>(obj, score_s, frame, feat);
    fused_gemm_tanh_score_f32<<<dim3(8, M_T / FBM), 256, 0, stream>>>(
        feat, t_wv_w, h_t, t_wa_w, score2, M_T, FEAT2, NFRAME);
  }

  temporal_out<<<BATCH, 256, 0, stream>>>(score2, feat, out);
}

// Round 4
// 748.754 us; speedup vs baseline: 2.1014x; 1.0544x over previous
//
#include <hip/hip_runtime.h>
#include <hip/hip_bf16.h>
#include <stdint.h>

#define BATCH  64
#define NFRAME 32
#define NBOX   36
#define REGION 1024
#define HIDDEN 1024
#define ATTSZ  1024
#define FEAT2  3072
#define M_S (BATCH * NFRAME * NBOX)   // 73728
#define M_T (BATCH * NFRAME)          // 2048

typedef __attribute__((ext_vector_type(8))) short bf16x8;
typedef __attribute__((ext_vector_type(4))) float f32x4;

__device__ __forceinline__ unsigned short f2bf(float f) {
  union { float f; uint32_t u; } v; v.f = f;
  return (unsigned short)((v.u + 0x7FFFu + ((v.u >> 16) & 1u)) >> 16);  // RNE
}
__device__ __forceinline__ float bf2f(unsigned short u) {
  union { uint32_t u; float f; } v; v.u = (uint32_t)u << 16; return v.f;
}
__device__ __forceinline__ float fast_tanh(float x) {
  float e = __expf(2.f * x);
  return 1.f - 2.f / (e + 1.f);
}
__device__ __forceinline__ void gload_lds16(const unsigned short* g, unsigned short* l) {
  __builtin_amdgcn_global_load_lds(
      (const __attribute__((address_space(1))) unsigned int*)g,
      (__attribute__((address_space(3))) unsigned int*)l, 16, 0, 0);
}

// ---------------------------------------------------------------------------
// fp32 -> bf16 cast, 8 elems/thread
// ---------------------------------------------------------------------------
__global__ __launch_bounds__(256) void cast_f32_bf16(
    const float* __restrict__ in, unsigned short* __restrict__ out, long n) {
  long i = ((long)blockIdx.x * 256 + threadIdx.x) * 8;
  if (i >= n) return;
  float4 a = *(const float4*)(in + i);
  float4 b = *(const float4*)(in + i + 4);
  ushort4 lo; lo.x = f2bf(a.x); lo.y = f2bf(a.y); lo.z = f2bf(a.z); lo.w = f2bf(a.w);
  ushort4 hi; hi.x = f2bf(b.x); hi.y = f2bf(b.y); hi.z = f2bf(b.z); hi.w = f2bf(b.w);
  *(ushort4*)(out + i) = lo;
  *(ushort4*)(out + i + 4) = hi;
}

// ---------------------------------------------------------------------------
// Templated bf16 GEMM + tanh + row-score reduction.
//   score[row] += sum_col tanh( (A @ W^T)[row][col] + h[b(row)][col] ) * wa[col]
// Block = 256 threads = 4 waves in 2x2; wave tile (TM*16) x (TN*16);
// block tile BM x BN, BK=64, global_load_lds staging.
// LDS layout XOR-swizzled: chunk c = 8 rows x 8 granules(16B); slot (r,p)
// holds logical granule p^r  -> bank-conflict-free fragment reads without
// padding (global_load_lds requires contiguous lane x 16B destinations).
// LINGRID: 1-D grid, col-siblings 8 apart so they share an XCD's L2 for A.
// REQUIRES: BM-aligned row tiles within one batch.
// ---------------------------------------------------------------------------
template<int TM, int TN, bool LINGRID, int NCOLT>
__global__ __launch_bounds__(256, 2) void gemm_tanh_score(
    const unsigned short* __restrict__ A, const unsigned short* __restrict__ W,
    const float* __restrict__ hvec, const float* __restrict__ wa,
    float* __restrict__ score, int K, int rows_per_b)
{
  constexpr int BM = 2 * TM * 16;
  constexpr int BN = 2 * TN * 16;
  __shared__ __align__(16) unsigned short ldsA[BM * 64];
  __shared__ __align__(16) unsigned short ldsW[BN * 64];
  __shared__ float h_tile[BN];
  __shared__ float score_sh[2][BM];

  const int tid  = threadIdx.x;
  const int lane = tid & 63;
  const int wid  = tid >> 6;
  const int wr   = (wid >> 1) * (TM * 16);
  const int wc   = (wid & 1) * (TN * 16);
  const int l15  = lane & 15;
  const int q    = lane >> 4;
  const int rl   = l15 & 7;         // fragment-read swizzle key
  const int srow = lane >> 3;       // staging: row within 8-row chunk
  const int sgr  = (lane & 7) ^ srow;  // staging: swizzled source granule

  long r0; int c0;
  if (LINGRID) {
    int bid = blockIdx.x;
    int rt = (bid & 7) + (bid >> (3 + (NCOLT == 4 ? 2 : 3))) * 8;
    int ct = (bid >> 3) & (NCOLT - 1);
    r0 = (long)rt * BM; c0 = ct * BN;
  } else {
    r0 = (long)blockIdx.y * BM; c0 = blockIdx.x * BN;
  }
  const int b0 = (int)(r0 / rows_per_b);   // tile lies in one batch

  for (int i = tid; i < BN; i += 256)
    h_tile[i] = hvec[(long)b0 * ATTSZ + c0 + i];
  float wac[TN];
  #pragma unroll
  for (int j = 0; j < TN; ++j) wac[j] = wa[c0 + wc + j * 16 + l15];

  f32x4 acc[TM][TN] = {};

  for (int k0 = 0; k0 < K; k0 += 64) {
    __syncthreads();
    #pragma unroll
    for (int it = 0; it < BM / 32; ++it) {
      int c = wid * (BM / 32) + it;
      gload_lds16(A + (r0 + c * 8 + srow) * (long)K + k0 + (sgr << 3), ldsA + c * 512);
    }
    #pragma unroll
    for (int it = 0; it < BN / 32; ++it) {
      int c = wid * (BN / 32) + it;
      gload_lds16(W + ((long)(c0 + c * 8 + srow)) * K + k0 + (sgr << 3), ldsW + c * 512);
    }
    __syncthreads();
    #pragma unroll
    for (int s = 0; s < 2; ++s) {
      bf16x8 af[TM], wf[TN];
      const int gsw = ((s * 4 + q) ^ rl) << 3;    // swizzled granule offset
      #pragma unroll
      for (int i = 0; i < TM; ++i)
        af[i] = *(const bf16x8*)(ldsA + (wr + i * 16 + l15) * 64 + gsw);
      #pragma unroll
      for (int j = 0; j < TN; ++j)
        wf[j] = *(const bf16x8*)(ldsW + (wc + j * 16 + l15) * 64 + gsw);
      #pragma unroll
      for (int i = 0; i < TM; ++i)
        #pragma unroll
        for (int j = 0; j < TN; ++j)
          acc[i][j] = __builtin_amdgcn_mfma_f32_16x16x32_bf16(af[i], wf[j], acc[i][j], 0, 0, 0);
    }
  }

  // Epilogue: tanh(acc + h) * wa, quad-reduce over the 16 col-lanes.
  #pragma unroll
  for (int i = 0; i < TM; ++i) {
    #pragma unroll
    for (int r = 0; r < 4; ++r) {
      float part = 0.f;
      #pragma unroll
      for (int j = 0; j < TN; ++j) {
        float x = acc[i][j][r] + h_tile[wc + j * 16 + l15];
        part += fast_tanh(x) * wac[j];
      }
      part += __shfl_xor(part, 1); part += __shfl_xor(part, 2);
      part += __shfl_xor(part, 4); part += __shfl_xor(part, 8);
      if (l15 == 0) score_sh[wid & 1][wr + i * 16 + q * 4 + r] = part;
    }
  }
  __syncthreads();
  if (tid < BM)
    atomicAdd(score + r0 + tid, score_sh[0][tid] + score_sh[1][tid]);
}

// ---------------------------------------------------------------------------
// h projections (biases folded)
// ---------------------------------------------------------------------------
__global__ __launch_bounds__(256) void hidden_proj(
    const float* __restrict__ hidden,
    const float* __restrict__ s_wh_w, const float* __restrict__ s_wh_b,
    const float* __restrict__ s_wv_b,
    const float* __restrict__ t_wh_w, const float* __restrict__ t_wh_b,
    const float* __restrict__ t_wv_b,
    float* __restrict__ h_s, float* __restrict__ h_t)
{
  const float *W, *b1, *b2;
  float* out;
  if (blockIdx.y == 0) { W = s_wh_w; b1 = s_wh_b; b2 = s_wv_b; out = h_s; }
  else                 { W = t_wh_w; b1 = t_wh_b; b2 = t_wv_b; out = h_t; }
  const int lane = threadIdx.x & 63;
  const int wid  = threadIdx.x >> 6;
  const int a    = blockIdx.x * 4 + wid;
  __shared__ float hs[64 * 256];
  float acc[64];
  #pragma unroll
  for (int b = 0; b < 64; ++b) acc[b] = 0.f;

  for (int dc = 0; dc < 4; ++dc) {
    __syncthreads();
    for (int i = threadIdx.x; i < 4096; i += 256) {
      int b = i >> 6, d4 = i & 63;
      *(float4*)(hs + b * 256 + d4 * 4) =
          *(const float4*)(hidden + b * 1024 + dc * 256 + d4 * 4);
    }
    __syncthreads();
    float4 w4 = *(const float4*)(W + (long)a * 1024 + dc * 256 + lane * 4);
    #pragma unroll
    for (int b = 0; b < 64; ++b) {
      float4 h4 = *(const float4*)(hs + b * 256 + lane * 4);
      acc[b] += w4.x * h4.x + w4.y * h4.y + w4.z * h4.z + w4.w * h4.w;
    }
  }
  #pragma unroll
  for (int b = 0; b < 64; ++b) {
    #pragma unroll
    for (int off = 1; off < 64; off <<= 1)
      acc[b] += __shfl_xor(acc[b], off);
  }
  float res = 0.f;
  #pragma unroll
  for (int b = 0; b < 64; ++b)
    if (lane == b) res = acc[b];
  out[lane * 1024 + a] = res + b1[a] + b2[a];
}

// ---------------------------------------------------------------------------
// Spatial softmax + weighted sum (bf16 obj) -> feat fp32 + feat bf16
// ---------------------------------------------------------------------------
__global__ __launch_bounds__(256) void spatial_softmax_obj_bf16(
    const unsigned short* __restrict__ objb, const float* __restrict__ score,
    const float* __restrict__ frame, float* __restrict__ feat,
    unsigned short* __restrict__ featb)
{
  const int bf = blockIdx.x;
  __shared__ float alpha[NBOX];
  if (threadIdx.x < 64) {
    int n = threadIdx.x;
    float v = (n < NBOX) ? score[bf * NBOX + n] : -1e30f;
    float m = v;
    #pragma unroll
    for (int off = 32; off; off >>= 1) m = fmaxf(m, __shfl_xor(m, off));
    float e = (n < NBOX) ? __expf(v - m) : 0.f;
    float ssum = e;
    #pragma unroll
    for (int off = 32; off; off >>= 1) ssum += __shfl_xor(ssum, off);
    if (n < NBOX) alpha[n] = e / ssum;
  }
  __syncthreads();
  const unsigned short* base = objb + (long)bf * NBOX * REGION;
  float4 av = {0.f, 0.f, 0.f, 0.f};
  #pragma unroll 4
  for (int n = 0; n < NBOX; ++n) {
    float al = alpha[n];
    ushort4 o = *(const ushort4*)(base + n * REGION + threadIdx.x * 4);
    av.x += al * bf2f(o.x); av.y += al * bf2f(o.y);
    av.z += al * bf2f(o.z); av.w += al * bf2f(o.w);
  }
  float* frow = feat + (long)bf * FEAT2;
  unsigned short* fbrow = featb + (long)bf * FEAT2;
  *(float4*)(frow + threadIdx.x * 4) = av;
  ushort4 avb; avb.x = f2bf(av.x); avb.y = f2bf(av.y); avb.z = f2bf(av.z); avb.w = f2bf(av.w);
  *(ushort4*)(fbrow + threadIdx.x * 4) = avb;
  const float* fsrc = frame + (long)bf * 2 * HIDDEN;
  #pragma unroll
  for (int c = 0; c < 2; ++c) {
    float4 v = *(const float4*)(fsrc + (threadIdx.x + c * 256) * 4);
    *(float4*)(frow + REGION + (threadIdx.x + c * 256) * 4) = v;
    ushort4 vb; vb.x = f2bf(v.x); vb.y = f2bf(v.y); vb.z = f2bf(v.z); vb.w = f2bf(v.w);
    *(ushort4*)(fbrow + REGION + (threadIdx.x + c * 256) * 4) = vb;
  }
}

// ---------------------------------------------------------------------------
// Temporal softmax + weighted sum of fp32 feat -> out[B, 3072]
// ---------------------------------------------------------------------------
__global__ __launch_bounds__(256) void temporal_out(
    const float* __restrict__ score2, const float* __restrict__ feat,
    float* __restrict__ out)
{
  const int b = blockIdx.x;
  __shared__ float beta[NFRAME];
  if (threadIdx.x < 64) {
    int f = threadIdx.x;
    float v = (f < NFRAME) ? score2[b * NFRAME + f] : -1e30f;
    float m = v;
    #pragma unroll
    for (int off = 32; off; off >>= 1) m = fmaxf(m, __shfl_xor(m, off));
    float e = (f < NFRAME) ? __expf(v - m) : 0.f;
    float ssum = e;
    #pragma unroll
    for (int off = 32; off; off >>= 1) ssum += __shfl_xor(ssum, off);
    if (f < NFRAME) beta[f] = e / ssum;
  }
  __syncthreads();
  #pragma unroll
  for (int c = 0; c < 3; ++c) {
    int col = (threadIdx.x + c * 256) * 4;
    float4 av = {0.f, 0.f, 0.f, 0.f};
    #pragma unroll 4
    for (int f = 0; f < NFRAME; ++f) {
      float bw = beta[f];
      float4 v = *(const float4*)(feat + (long)(b * NFRAME + f) * FEAT2 + col);
      av.x += bw * v.x; av.y += bw * v.y; av.z += bw * v.z; av.w += bw * v.w;
    }
    *(float4*)(out + (long)b * FEAT2 + col) = av;
  }
}

// ===========================================================================
// Fallback path (fp32 inputs, inline conversion) — only if ws too small.
// ===========================================================================
#define FBM 128
#define FBN 128
#define FBK 64
#define LDKP 72
__global__ __launch_bounds__(256) void fused_gemm_tanh_score_f32(
    const float* __restrict__ A, const float* __restrict__ W,
    const float* __restrict__ hvec, const float* __restrict__ wa,
    float* __restrict__ score, int M, int K, int rows_per_b)
{
  __shared__ unsigned short ldsA[FBM * LDKP];
  __shared__ unsigned short ldsW[FBN * LDKP];
  const int tid  = threadIdx.x;
  const int lane = tid & 63;
  const int wid  = tid >> 6;
  const int wr   = (wid >> 1) * 64;
  const int wc   = (wid & 1) * 64;
  const int l15  = lane & 15;
  const int q    = lane >> 4;
  const long r0  = (long)blockIdx.y * FBM;
  const int  c0  = blockIdx.x * FBN;

  f32x4 acc[4][4] = {};
  for (int k0 = 0; k0 < K; k0 += FBK) {
    __syncthreads();
    #pragma unroll
    for (int it = 0; it < 8; ++it) {
      int c = tid + it * 256;
      int row = c >> 4, qb = c & 15;
      float4 s = *(const float4*)(A + (r0 + row) * (long)K + k0 + qb * 4);
      ushort4 d; d.x = f2bf(s.x); d.y = f2bf(s.y); d.z = f2bf(s.z); d.w = f2bf(s.w);
      *(ushort4*)(ldsA + row * LDKP + qb * 4) = d;
    }
    #pragma unroll
    for (int it = 0; it < 8; ++it) {
      int c = tid + it * 256;
      int row = c >> 4, qb = c & 15;
      float4 s = *(const float4*)(W + (c0 + row) * (long)K + k0 + qb * 4);
      ushort4 d; d.x = f2bf(s.x); d.y = f2bf(s.y); d.z = f2bf(s.z); d.w = f2bf(s.w);
      *(ushort4*)(ldsW + row * LDKP + qb * 4) = d;
    }
    __syncthreads();
    #pragma unroll
    for (int s = 0; s < 2; ++s) {
      bf16x8 af[4], bfr[4];
      #pragma unroll
      for (int i = 0; i < 4; ++i)
        af[i] = *(const bf16x8*)(ldsA + (wr + i * 16 + l15) * LDKP + s * 32 + q * 8);
      #pragma unroll
      for (int j = 0; j < 4; ++j)
        bfr[j] = *(const bf16x8*)(ldsW + (wc + j * 16 + l15) * LDKP + s * 32 + q * 8);
      #pragma unroll
      for (int i = 0; i < 4; ++i)
        #pragma unroll
        for (int j = 0; j < 4; ++j)
          acc[i][j] = __builtin_amdgcn_mfma_f32_16x16x32_bf16(af[i], bfr[j], acc[i][j], 0, 0, 0);
    }
  }
  float wac[4];
  #pragma unroll
  for (int j = 0; j < 4; ++j) wac[j] = wa[c0 + wc + j * 16 + l15];
  #pragma unroll
  for (int i = 0; i < 4; ++i) {
    #pragma unroll
    for (int r = 0; r < 4; ++r) {
      int row = (int)r0 + wr + i * 16 + q * 4 + r;
      const float* hrow = hvec + (long)(row / rows_per_b) * ATTSZ;
      float part = 0.f;
      #pragma unroll
      for (int j = 0; j < 4; ++j) {
        float x = acc[i][j][r] + hrow[c0 + wc + j * 16 + l15];
        part += fast_tanh(x) * wac[j];
      }
      part += __shfl_xor(part, 1); part += __shfl_xor(part, 2);
      part += __shfl_xor(part, 4); part += __shfl_xor(part, 8);
      if (l15 == 0) atomicAdd(score + row, part);
    }
  }
}

__global__ __launch_bounds__(256) void spatial_softmax_obj_f32(
    const float* __restrict__ obj, const float* __restrict__ score,
    const float* __restrict__ frame, float* __restrict__ feat)
{
  const int bf = blockIdx.x;
  __shared__ float alpha[NBOX];
  if (threadIdx.x < 64) {
    int n = threadIdx.x;
    float v = (n < NBOX) ? score[bf * NBOX + n] : -1e30f;
    float m = v;
    #pragma unroll
    for (int off = 32; off; off >>= 1) m = fmaxf(m, __shfl_xor(m, off));
    float e = (n < NBOX) ? __expf(v - m) : 0.f;
    float ssum = e;
    #pragma unroll
    for (int off = 32; off; off >>= 1) ssum += __shfl_xor(ssum, off);
    if (n < NBOX) alpha[n] = e / ssum;
  }
  __syncthreads();
  const float* base = obj + (long)bf * NBOX * REGION;
  float4 av = {0.f, 0.f, 0.f, 0.f};
  for (int n = 0; n < NBOX; ++n) {
    float al = alpha[n];
    float4 o = *(const float4*)(base + n * REGION + threadIdx.x * 4);
    av.x += al * o.x; av.y += al * o.y; av.z += al * o.z; av.w += al * o.w;
  }
  float* frow = feat + (long)bf * FEAT2;
  *(float4*)(frow + threadIdx.x * 4) = av;
  const float4* fsrc = (const float4*)(frame + (long)bf * 2 * HIDDEN);
  float4* fdst = (float4*)(frow + REGION);
  fdst[threadIdx.x]       = fsrc[threadIdx.x];
  fdst[threadIdx.x + 256] = fsrc[threadIdx.x + 256];
}

// ---------------------------------------------------------------------------
extern "C" void kernel_launch(void* const* d_in, const int* in_sizes, int n_in,
                              void* d_out, int out_size, void* d_ws, size_t ws_size,
                              hipStream_t stream) {
  const float* frame  = (const float*)d_in[0];
  const float* obj    = (const float*)d_in[1];
  const float* hidden = (const float*)d_in[2];
  const float* s_wh_w = (const float*)d_in[3];
  const float* s_wh_b = (const float*)d_in[4];
  const float* s_wv_w = (const float*)d_in[5];
  const float* s_wv_b = (const float*)d_in[6];
  const float* s_wa_w = (const float*)d_in[7];
  const float* t_wh_w = (const float*)d_in[8];
  const float* t_wh_b = (const float*)d_in[9];
  const float* t_wv_w = (const float*)d_in[10];
  const float* t_wv_b = (const float*)d_in[11];
  const float* t_wa_w = (const float*)d_in[12];
  float* out = (float*)d_out;

  char* p = (char*)d_ws;
  auto alloc = [&](size_t bytes) { char* r = p; p += (bytes + 255) & ~255ull; return r; };
  float* h_s     = (float*)alloc(65536 * 4);
  float* h_t     = (float*)alloc(65536 * 4);
  float* score_s = (float*)alloc((size_t)M_S * 4);   // contiguous with score2
  float* score2  = (float*)alloc((size_t)M_T * 4);
  float* feat    = (float*)alloc((size_t)M_T * FEAT2 * 4);
  unsigned short* objb  = (unsigned short*)alloc((size_t)M_S * REGION * 2);
  unsigned short* featb = (unsigned short*)alloc((size_t)M_T * FEAT2 * 2);
  unsigned short* wvsb  = (unsigned short*)alloc((size_t)ATTSZ * REGION * 2);
  unsigned short* wvtb  = (unsigned short*)alloc((size_t)HIDDEN * FEAT2 * 2);
  size_t needed = (size_t)(p - (char*)d_ws);
  bool fast = needed <= ws_size;

  hipMemsetAsync(score_s, 0, (size_t)(M_S + M_T) * sizeof(float), stream);
  hidden_proj<<<dim3(256, 2), 256, 0, stream>>>(
      hidden, s_wh_w, s_wh_b, s_wv_b, t_wh_w, t_wh_b, t_wv_b, h_s, h_t);

  if (fast) {
    cast_f32_bf16<<<(M_S * (long)REGION) / 2048, 256, 0, stream>>>(obj, objb, (long)M_S * REGION);
    cast_f32_bf16<<<(ATTSZ * (long)REGION) / 2048, 256, 0, stream>>>(s_wv_w, wvsb, (long)ATTSZ * REGION);
    cast_f32_bf16<<<(HIDDEN * (long)FEAT2) / 2048, 256, 0, stream>>>(t_wv_w, wvtb, (long)HIDDEN * FEAT2);

    // Spatial: 128x256 tiles, 1-D grid, 4 col-siblings co-located per XCD.
    gemm_tanh_score<4, 8, true, 4><<<dim3(4 * (M_S / 128)), 256, 0, stream>>>(
        objb, wvsb, h_s, s_wa_w, score_s, REGION, NFRAME * NBOX);

    spatial_softmax_obj_bf16<<<M_T, 256, 0, stream>>>(objb, score_s, frame, feat, featb);

    // Temporal: 32x128 tiles, grid (8, 64) = 512 blocks (2/CU).
    gemm_tanh_score<1, 4, false, 8><<<dim3(8, M_T / 32), 256, 0, stream>>>(
        featb, wvtb, h_t, t_wa_w, score2, FEAT2, NFRAME);
  } else {
    fused_gemm_tanh_score_f32<<<dim3(8, M_S / FBM), 256, 0, stream>>>(
        obj, s_wv_w, h_s, s_wa_w, score_s, M_S, REGION, NFRAME * NBOX);
    spatial_softmax_obj_f32<<<M_T, 256, 0, stream>>>(obj, score_s, frame, feat);
    fused_gemm_tanh_score_f32<<<dim3(8, M_T / FBM), 256, 0, stream>>>(
        feat, t_wv_w, h_t, t_wa_w, score2, M_T, FEAT2, NFRAME);
  }

  temporal_out<<<BATCH, 256, 0, stream>>>(score2, feat, out);
}

// Round 5
// 733.804 us; speedup vs baseline: 2.1442x; 1.0204x over previous
//
#include <hip/hip_runtime.h>
#include <hip/hip_bf16.h>
#include <stdint.h>

#define BATCH  64
#define NFRAME 32
#define NBOX   36
#define REGION 1024
#define HIDDEN 1024
#define ATTSZ  1024
#define FEAT2  3072
#define M_S (BATCH * NFRAME * NBOX)   // 73728
#define M_T (BATCH * NFRAME)          // 2048

typedef __attribute__((ext_vector_type(8))) short bf16x8;
typedef __attribute__((ext_vector_type(4))) float f32x4;

__device__ __forceinline__ unsigned short f2bf(float f) {
  union { float f; uint32_t u; } v; v.f = f;
  return (unsigned short)((v.u + 0x7FFFu + ((v.u >> 16) & 1u)) >> 16);  // RNE
}
__device__ __forceinline__ float bf2f(unsigned short u) {
  union { uint32_t u; float f; } v; v.u = (uint32_t)u << 16; return v.f;
}
__device__ __forceinline__ float fast_tanh(float x) {
  float e = __expf(2.f * x);
  return 1.f - 2.f / (e + 1.f);
}
__device__ __forceinline__ void gload_lds16(const unsigned short* g, unsigned short* l) {
  __builtin_amdgcn_global_load_lds(
      (const __attribute__((address_space(1))) unsigned int*)g,
      (__attribute__((address_space(3))) unsigned int*)l, 16, 0, 0);
}
constexpr int clog2(int v) { return v <= 1 ? 0 : 1 + clog2(v >> 1); }

// ---------------------------------------------------------------------------
// fp32 -> bf16 cast, 8 elems/thread
// ---------------------------------------------------------------------------
__global__ __launch_bounds__(256) void cast_f32_bf16(
    const float* __restrict__ in, unsigned short* __restrict__ out, long n) {
  long i = ((long)blockIdx.x * 256 + threadIdx.x) * 8;
  if (i >= n) return;
  float4 a = *(const float4*)(in + i);
  float4 b = *(const float4*)(in + i + 4);
  ushort4 lo; lo.x = f2bf(a.x); lo.y = f2bf(a.y); lo.z = f2bf(a.z); lo.w = f2bf(a.w);
  ushort4 hi; hi.x = f2bf(b.x); hi.y = f2bf(b.y); hi.z = f2bf(b.z); hi.w = f2bf(b.w);
  *(ushort4*)(out + i) = lo;
  *(ushort4*)(out + i + 4) = hi;
}

// ---------------------------------------------------------------------------
// Templated bf16 GEMM + tanh + row-score reduction.
//   score[row] += sum_col tanh( (A @ W^T)[row][col] + h[b(row)][col] ) * wa[col]
// Block = 256 threads = 4 waves in 2x2; wave tile (TM*16) x (TN*16);
// block tile BM x BN, BK=64, global_load_lds staging.
// LDS XOR-swizzle: chunk = 8 rows x 8 granules(16B); slot (r,p) holds logical
// granule p^r -> conflict-free reads without padding (measured R4: 4.2e7 -> 0).
// LINGRID: bid%8 selects XCD (round-robin); col-siblings placed 8 apart so
// a row-tile's A lives in ONE XCD L2 (measured R4: FETCH 305->107 MB).
// __launch_bounds__(256,3): cap regs ~170 so 3 blocks/CU co-reside (m103).
// REQUIRES: BM-aligned row tiles within one batch.
// ---------------------------------------------------------------------------
template<int TM, int TN, bool LINGRID, int NCOLT>
__global__ __launch_bounds__(256, 3) void gemm_tanh_score(
    const unsigned short* __restrict__ A, const unsigned short* __restrict__ W,
    const float* __restrict__ hvec, const float* __restrict__ wa,
    float* __restrict__ score, int K, int rows_per_b)
{
  constexpr int BM = 2 * TM * 16;
  constexpr int BN = 2 * TN * 16;
  __shared__ __align__(16) unsigned short ldsA[BM * 64];
  __shared__ __align__(16) unsigned short ldsW[BN * 64];
  __shared__ float h_tile[BN];
  __shared__ float score_sh[2][BM];

  const int tid  = threadIdx.x;
  const int lane = tid & 63;
  const int wid  = tid >> 6;
  const int wr   = (wid >> 1) * (TM * 16);
  const int wc   = (wid & 1) * (TN * 16);
  const int l15  = lane & 15;
  const int q    = lane >> 4;
  const int rl   = l15 & 7;            // fragment-read swizzle key
  const int srow = lane >> 3;          // staging: row within 8-row chunk
  const int sgr  = (lane & 7) ^ srow;  // staging: swizzled source granule

  long r0; int c0;
  if (LINGRID) {
    int bid = blockIdx.x;
    int rt = (bid & 7) + (bid >> (3 + clog2(NCOLT))) * 8;
    int ct = (bid >> 3) & (NCOLT - 1);
    r0 = (long)rt * BM; c0 = ct * BN;
  } else {
    r0 = (long)blockIdx.y * BM; c0 = blockIdx.x * BN;
  }
  const int b0 = (int)(r0 / rows_per_b);   // tile lies in one batch

  for (int i = tid; i < BN; i += 256)
    h_tile[i] = hvec[(long)b0 * ATTSZ + c0 + i];
  float wac[TN];
  #pragma unroll
  for (int j = 0; j < TN; ++j) wac[j] = wa[c0 + wc + j * 16 + l15];

  f32x4 acc[TM][TN] = {};

  for (int k0 = 0; k0 < K; k0 += 64) {
    __syncthreads();
    #pragma unroll
    for (int it = 0; it < BM / 32; ++it) {
      int c = wid * (BM / 32) + it;
      gload_lds16(A + (r0 + c * 8 + srow) * (long)K + k0 + (sgr << 3), ldsA + c * 512);
    }
    #pragma unroll
    for (int it = 0; it < BN / 32; ++it) {
      int c = wid * (BN / 32) + it;
      gload_lds16(W + ((long)(c0 + c * 8 + srow)) * K + k0 + (sgr << 3), ldsW + c * 512);
    }
    __syncthreads();
    #pragma unroll
    for (int s = 0; s < 2; ++s) {
      bf16x8 af[TM], wf[TN];
      const int gsw = ((s * 4 + q) ^ rl) << 3;    // swizzled granule offset
      #pragma unroll
      for (int i = 0; i < TM; ++i)
        af[i] = *(const bf16x8*)(ldsA + (wr + i * 16 + l15) * 64 + gsw);
      #pragma unroll
      for (int j = 0; j < TN; ++j)
        wf[j] = *(const bf16x8*)(ldsW + (wc + j * 16 + l15) * 64 + gsw);
      #pragma unroll
      for (int i = 0; i < TM; ++i)
        #pragma unroll
        for (int j = 0; j < TN; ++j)
          acc[i][j] = __builtin_amdgcn_mfma_f32_16x16x32_bf16(af[i], wf[j], acc[i][j], 0, 0, 0);
    }
  }

  // Epilogue: tanh(acc + h) * wa, quad-reduce over the 16 col-lanes.
  #pragma unroll
  for (int i = 0; i < TM; ++i) {
    #pragma unroll
    for (int r = 0; r < 4; ++r) {
      float part = 0.f;
      #pragma unroll
      for (int j = 0; j < TN; ++j) {
        float x = acc[i][j][r] + h_tile[wc + j * 16 + l15];
        part += fast_tanh(x) * wac[j];
      }
      part += __shfl_xor(part, 1); part += __shfl_xor(part, 2);
      part += __shfl_xor(part, 4); part += __shfl_xor(part, 8);
      if (l15 == 0) score_sh[wid & 1][wr + i * 16 + q * 4 + r] = part;
    }
  }
  __syncthreads();
  if (tid < BM)
    atomicAdd(score + r0 + tid, score_sh[0][tid] + score_sh[1][tid]);
}

// ---------------------------------------------------------------------------
// h projections (biases folded)
// ---------------------------------------------------------------------------
__global__ __launch_bounds__(256) void hidden_proj(
    const float* __restrict__ hidden,
    const float* __restrict__ s_wh_w, const float* __restrict__ s_wh_b,
    const float* __restrict__ s_wv_b,
    const float* __restrict__ t_wh_w, const float* __restrict__ t_wh_b,
    const float* __restrict__ t_wv_b,
    float* __restrict__ h_s, float* __restrict__ h_t)
{
  const float *W, *b1, *b2;
  float* out;
  if (blockIdx.y == 0) { W = s_wh_w; b1 = s_wh_b; b2 = s_wv_b; out = h_s; }
  else                 { W = t_wh_w; b1 = t_wh_b; b2 = t_wv_b; out = h_t; }
  const int lane = threadIdx.x & 63;
  const int wid  = threadIdx.x >> 6;
  const int a    = blockIdx.x * 4 + wid;
  __shared__ float hs[64 * 256];
  float acc[64];
  #pragma unroll
  for (int b = 0; b < 64; ++b) acc[b] = 0.f;

  for (int dc = 0; dc < 4; ++dc) {
    __syncthreads();
    for (int i = threadIdx.x; i < 4096; i += 256) {
      int b = i >> 6, d4 = i & 63;
      *(float4*)(hs + b * 256 + d4 * 4) =
          *(const float4*)(hidden + b * 1024 + dc * 256 + d4 * 4);
    }
    __syncthreads();
    float4 w4 = *(const float4*)(W + (long)a * 1024 + dc * 256 + lane * 4);
    #pragma unroll
    for (int b = 0; b < 64; ++b) {
      float4 h4 = *(const float4*)(hs + b * 256 + lane * 4);
      acc[b] += w4.x * h4.x + w4.y * h4.y + w4.z * h4.z + w4.w * h4.w;
    }
  }
  #pragma unroll
  for (int b = 0; b < 64; ++b) {
    #pragma unroll
    for (int off = 1; off < 64; off <<= 1)
      acc[b] += __shfl_xor(acc[b], off);
  }
  float res = 0.f;
  #pragma unroll
  for (int b = 0; b < 64; ++b)
    if (lane == b) res = acc[b];
  out[lane * 1024 + a] = res + b1[a] + b2[a];
}

// ---------------------------------------------------------------------------
// Spatial softmax + weighted sum (bf16 obj) -> feat fp32 + feat bf16
// ---------------------------------------------------------------------------
__global__ __launch_bounds__(256) void spatial_softmax_obj_bf16(
    const unsigned short* __restrict__ objb, const float* __restrict__ score,
    const float* __restrict__ frame, float* __restrict__ feat,
    unsigned short* __restrict__ featb)
{
  const int bf = blockIdx.x;
  __shared__ float alpha[NBOX];
  if (threadIdx.x < 64) {
    int n = threadIdx.x;
    float v = (n < NBOX) ? score[bf * NBOX + n] : -1e30f;
    float m = v;
    #pragma unroll
    for (int off = 32; off; off >>= 1) m = fmaxf(m, __shfl_xor(m, off));
    float e = (n < NBOX) ? __expf(v - m) : 0.f;
    float ssum = e;
    #pragma unroll
    for (int off = 32; off; off >>= 1) ssum += __shfl_xor(ssum, off);
    if (n < NBOX) alpha[n] = e / ssum;
  }
  __syncthreads();
  const unsigned short* base = objb + (long)bf * NBOX * REGION;
  float4 av = {0.f, 0.f, 0.f, 0.f};
  #pragma unroll 4
  for (int n = 0; n < NBOX; ++n) {
    float al = alpha[n];
    ushort4 o = *(const ushort4*)(base + n * REGION + threadIdx.x * 4);
    av.x += al * bf2f(o.x); av.y += al * bf2f(o.y);
    av.z += al * bf2f(o.z); av.w += al * bf2f(o.w);
  }
  float* frow = feat + (long)bf * FEAT2;
  unsigned short* fbrow = featb + (long)bf * FEAT2;
  *(float4*)(frow + threadIdx.x * 4) = av;
  ushort4 avb; avb.x = f2bf(av.x); avb.y = f2bf(av.y); avb.z = f2bf(av.z); avb.w = f2bf(av.w);
  *(ushort4*)(fbrow + threadIdx.x * 4) = avb;
  const float* fsrc = frame + (long)bf * 2 * HIDDEN;
  #pragma unroll
  for (int c = 0; c < 2; ++c) {
    float4 v = *(const float4*)(fsrc + (threadIdx.x + c * 256) * 4);
    *(float4*)(frow + REGION + (threadIdx.x + c * 256) * 4) = v;
    ushort4 vb; vb.x = f2bf(v.x); vb.y = f2bf(v.y); vb.z = f2bf(v.z); vb.w = f2bf(v.w);
    *(ushort4*)(fbrow + REGION + (threadIdx.x + c * 256) * 4) = vb;
  }
}

// ---------------------------------------------------------------------------
// Temporal softmax + weighted sum of fp32 feat -> out[B, 3072]
// grid (64, 3): blockIdx.y picks a 1024-col chunk (3x parallelism vs R4).
// ---------------------------------------------------------------------------
__global__ __launch_bounds__(256) void temporal_out(
    const float* __restrict__ score2, const float* __restrict__ feat,
    float* __restrict__ out)
{
  const int b = blockIdx.x;
  __shared__ float beta[NFRAME];
  if (threadIdx.x < 64) {
    int f = threadIdx.x;
    float v = (f < NFRAME) ? score2[b * NFRAME + f] : -1e30f;
    float m = v;
    #pragma unroll
    for (int off = 32; off; off >>= 1) m = fmaxf(m, __shfl_xor(m, off));
    float e = (f < NFRAME) ? __expf(v - m) : 0.f;
    float ssum = e;
    #pragma unroll
    for (int off = 32; off; off >>= 1) ssum += __shfl_xor(ssum, off);
    if (f < NFRAME) beta[f] = e / ssum;
  }
  __syncthreads();
  int col = blockIdx.y * 1024 + threadIdx.x * 4;
  float4 av = {0.f, 0.f, 0.f, 0.f};
  #pragma unroll 4
  for (int f = 0; f < NFRAME; ++f) {
    float bw = beta[f];
    float4 v = *(const float4*)(feat + (long)(b * NFRAME + f) * FEAT2 + col);
    av.x += bw * v.x; av.y += bw * v.y; av.z += bw * v.z; av.w += bw * v.w;
  }
  *(float4*)(out + (long)b * FEAT2 + col) = av;
}

// ===========================================================================
// Fallback path (fp32 inputs, inline conversion) — only if ws too small.
// ===========================================================================
#define FBM 128
#define FBN 128
#define FBK 64
#define LDKP 72
__global__ __launch_bounds__(256) void fused_gemm_tanh_score_f32(
    const float* __restrict__ A, const float* __restrict__ W,
    const float* __restrict__ hvec, const float* __restrict__ wa,
    float* __restrict__ score, int M, int K, int rows_per_b)
{
  __shared__ unsigned short ldsA[FBM * LDKP];
  __shared__ unsigned short ldsW[FBN * LDKP];
  const int tid  = threadIdx.x;
  const int lane = tid & 63;
  const int wid  = tid >> 6;
  const int wr   = (wid >> 1) * 64;
  const int wc   = (wid & 1) * 64;
  const int l15  = lane & 15;
  const int q    = lane >> 4;
  const long r0  = (long)blockIdx.y * FBM;
  const int  c0  = blockIdx.x * FBN;

  f32x4 acc[4][4] = {};
  for (int k0 = 0; k0 < K; k0 += FBK) {
    __syncthreads();
    #pragma unroll
    for (int it = 0; it < 8; ++it) {
      int c = tid + it * 256;
      int row = c >> 4, qb = c & 15;
      float4 s = *(const float4*)(A + (r0 + row) * (long)K + k0 + qb * 4);
      ushort4 d; d.x = f2bf(s.x); d.y = f2bf(s.y); d.z = f2bf(s.z); d.w = f2bf(s.w);
      *(ushort4*)(ldsA + row * LDKP + qb * 4) = d;
    }
    #pragma unroll
    for (int it = 0; it < 8; ++it) {
      int c = tid + it * 256;
      int row = c >> 4, qb = c & 15;
      float4 s = *(const float4*)(W + (c0 + row) * (long)K + k0 + qb * 4);
      ushort4 d; d.x = f2bf(s.x); d.y = f2bf(s.y); d.z = f2bf(s.z); d.w = f2bf(s.w);
      *(ushort4*)(ldsW + row * LDKP + qb * 4) = d;
    }
    __syncthreads();
    #pragma unroll
    for (int s = 0; s < 2; ++s) {
      bf16x8 af[4], bfr[4];
      #pragma unroll
      for (int i = 0; i < 4; ++i)
        af[i] = *(const bf16x8*)(ldsA + (wr + i * 16 + l15) * LDKP + s * 32 + q * 8);
      #pragma unroll
      for (int j = 0; j < 4; ++j)
        bfr[j] = *(const bf16x8*)(ldsW + (wc + j * 16 + l15) * LDKP + s * 32 + q * 8);
      #pragma unroll
      for (int i = 0; i < 4; ++i)
        #pragma unroll
        for (int j = 0; j < 4; ++j)
          acc[i][j] = __builtin_amdgcn_mfma_f32_16x16x32_bf16(af[i], bfr[j], acc[i][j], 0, 0, 0);
    }
  }
  float wac[4];
  #pragma unroll
  for (int j = 0; j < 4; ++j) wac[j] = wa[c0 + wc + j * 16 + l15];
  #pragma unroll
  for (int i = 0; i < 4; ++i) {
    #pragma unroll
    for (int r = 0; r < 4; ++r) {
      int row = (int)r0 + wr + i * 16 + q * 4 + r;
      const float* hrow = hvec + (long)(row / rows_per_b) * ATTSZ;
      float part = 0.f;
      #pragma unroll
      for (int j = 0; j < 4; ++j) {
        float x = acc[i][j][r] + hrow[c0 + wc + j * 16 + l15];
        part += fast_tanh(x) * wac[j];
      }
      part += __shfl_xor(part, 1); part += __shfl_xor(part, 2);
      part += __shfl_xor(part, 4); part += __shfl_xor(part, 8);
      if (l15 == 0) atomicAdd(score + row, part);
    }
  }
}

__global__ __launch_bounds__(256) void spatial_softmax_obj_f32(
    const float* __restrict__ obj, const float* __restrict__ score,
    const float* __restrict__ frame, float* __restrict__ feat)
{
  const int bf = blockIdx.x;
  __shared__ float alpha[NBOX];
  if (threadIdx.x < 64) {
    int n = threadIdx.x;
    float v = (n < NBOX) ? score[bf * NBOX + n] : -1e30f;
    float m = v;
    #pragma unroll
    for (int off = 32; off; off >>= 1) m = fmaxf(m, __shfl_xor(m, off));
    float e = (n < NBOX) ? __expf(v - m) : 0.f;
    float ssum = e;
    #pragma unroll
    for (int off = 32; off; off >>= 1) ssum += __shfl_xor(ssum, off);
    if (n < NBOX) alpha[n] = e / ssum;
  }
  __syncthreads();
  const float* base = obj + (long)bf * NBOX * REGION;
  float4 av = {0.f, 0.f, 0.f, 0.f};
  for (int n = 0; n < NBOX; ++n) {
    float al = alpha[n];
    float4 o = *(const float4*)(base + n * REGION + threadIdx.x * 4);
    av.x += al * o.x; av.y += al * o.y; av.z += al * o.z; av.w += al * o.w;
  }
  float* frow = feat + (long)bf * FEAT2;
  *(float4*)(frow + threadIdx.x * 4) = av;
  const float4* fsrc = (const float4*)(frame + (long)bf * 2 * HIDDEN);
  float4* fdst = (float4*)(frow + REGION);
  fdst[threadIdx.x]       = fsrc[threadIdx.x];
  fdst[threadIdx.x + 256] = fsrc[threadIdx.x + 256];
}

__global__ __launch_bounds__(256) void temporal_out_f32(
    const float* __restrict__ score2, const float* __restrict__ feat,
    float* __restrict__ out)
{
  const int b = blockIdx.x;
  __shared__ float beta[NFRAME];
  if (threadIdx.x < 64) {
    int f = threadIdx.x;
    float v = (f < NFRAME) ? score2[b * NFRAME + f] : -1e30f;
    float m = v;
    #pragma unroll
    for (int off = 32; off; off >>= 1) m = fmaxf(m, __shfl_xor(m, off));
    float e = (f < NFRAME) ? __expf(v - m) : 0.f;
    float ssum = e;
    #pragma unroll
    for (int off = 32; off; off >>= 1) ssum += __shfl_xor(ssum, off);
    if (f < NFRAME) beta[f] = e / ssum;
  }
  __syncthreads();
  #pragma unroll
  for (int c = 0; c < 3; ++c) {
    int col = (threadIdx.x + c * 256) * 4;
    float4 av = {0.f, 0.f, 0.f, 0.f};
    for (int f = 0; f < NFRAME; ++f) {
      float bw = beta[f];
      float4 v = *(const float4*)(feat + (long)(b * NFRAME + f) * FEAT2 + col);
      av.x += bw * v.x; av.y += bw * v.y; av.z += bw * v.z; av.w += bw * v.w;
    }
    *(float4*)(out + (long)b * FEAT2 + col) = av;
  }
}

// ---------------------------------------------------------------------------
extern "C" void kernel_launch(void* const* d_in, const int* in_sizes, int n_in,
                              void* d_out, int out_size, void* d_ws, size_t ws_size,
                              hipStream_t stream) {
  const float* frame  = (const float*)d_in[0];
  const float* obj    = (const float*)d_in[1];
  const float* hidden = (const float*)d_in[2];
  const float* s_wh_w = (const float*)d_in[3];
  const float* s_wh_b = (const float*)d_in[4];
  const float* s_wv_w = (const float*)d_in[5];
  const float* s_wv_b = (const float*)d_in[6];
  const float* s_wa_w = (const float*)d_in[7];
  const float* t_wh_w = (const float*)d_in[8];
  const float* t_wh_b = (const float*)d_in[9];
  const float* t_wv_w = (const float*)d_in[10];
  const float* t_wv_b = (const float*)d_in[11];
  const float* t_wa_w = (const float*)d_in[12];
  float* out = (float*)d_out;

  char* p = (char*)d_ws;
  auto alloc = [&](size_t bytes) { char* r = p; p += (bytes + 255) & ~255ull; return r; };
  float* h_s     = (float*)alloc(65536 * 4);
  float* h_t     = (float*)alloc(65536 * 4);
  float* score_s = (float*)alloc((size_t)M_S * 4);   // contiguous with score2
  float* score2  = (float*)alloc((size_t)M_T * 4);
  float* feat    = (float*)alloc((size_t)M_T * FEAT2 * 4);
  unsigned short* objb  = (unsigned short*)alloc((size_t)M_S * REGION * 2);
  unsigned short* featb = (unsigned short*)alloc((size_t)M_T * FEAT2 * 2);
  unsigned short* wvsb  = (unsigned short*)alloc((size_t)ATTSZ * REGION * 2);
  unsigned short* wvtb  = (unsigned short*)alloc((size_t)HIDDEN * FEAT2 * 2);
  size_t needed = (size_t)(p - (char*)d_ws);
  bool fast = needed <= ws_size;

  hipMemsetAsync(score_s, 0, (size_t)(M_S + M_T) * sizeof(float), stream);
  hidden_proj<<<dim3(256, 2), 256, 0, stream>>>(
      hidden, s_wh_w, s_wh_b, s_wv_b, t_wh_w, t_wh_b, t_wv_b, h_s, h_t);

  if (fast) {
    cast_f32_bf16<<<(M_S * (long)REGION) / 2048, 256, 0, stream>>>(obj, objb, (long)M_S * REGION);
    cast_f32_bf16<<<(ATTSZ * (long)REGION) / 2048, 256, 0, stream>>>(s_wv_w, wvsb, (long)ATTSZ * REGION);
    cast_f32_bf16<<<(HIDDEN * (long)FEAT2) / 2048, 256, 0, stream>>>(t_wv_w, wvtb, (long)HIDDEN * FEAT2);

    // Spatial: 128x128 tiles, 1-D grid, 8 col-siblings co-located per XCD,
    // 3 blocks/CU via __launch_bounds__(256,3).
    gemm_tanh_score<4, 4, true, 8><<<dim3(8 * (M_S / 128)), 256, 0, stream>>>(
        objb, wvsb, h_s, s_wa_w, score_s, REGION, NFRAME * NBOX);

    spatial_softmax_obj_bf16<<<M_T, 256, 0, stream>>>(objb, score_s, frame, feat, featb);

    // Temporal: 32x128 tiles, grid (8, 64) = 512 blocks.
    gemm_tanh_score<1, 4, false, 8><<<dim3(8, M_T / 32), 256, 0, stream>>>(
        featb, wvtb, h_t, t_wa_w, score2, FEAT2, NFRAME);

    temporal_out<<<dim3(BATCH, 3), 256, 0, stream>>>(score2, feat, out);
  } else {
    fused_gemm_tanh_score_f32<<<dim3(8, M_S / FBM), 256, 0, stream>>>(
        obj, s_wv_w, h_s, s_wa_w, score_s, M_S, REGION, NFRAME * NBOX);
    spatial_softmax_obj_f32<<<M_T, 256, 0, stream>>>(obj, score_s, frame, feat);
    fused_gemm_tanh_score_f32<<<dim3(8, M_T / FBM), 256, 0, stream>>>(
        feat, t_wv_w, h_t, t_wa_w, score2, M_T, FEAT2, NFRAME);
    temporal_out_f32<<<BATCH, 256, 0, stream>>>(score2, feat, out);
  }
}